// Round 4
// baseline (2091.950 us; speedup 1.0000x reference)
//
#include <hip/hip_runtime.h>
#include <cfloat>
#include <math.h>

#define B_ 8
#define N_ 4096
#define D_ 64
#define S_ 1024
#define K_ 32
#define CIN_ 131  // 2*D + 3

typedef float f32x2 __attribute__((ext_vector_type(2)));

// Move a u64 across lanes with a constant DPP control (2x 32-bit update_dpp).
template <int CTRL>
__device__ __forceinline__ unsigned long long dpp_u64(unsigned long long k) {
  int lo = (int)(unsigned int)k, hi = (int)(unsigned int)(k >> 32);
  lo = __builtin_amdgcn_update_dpp(lo, lo, CTRL, 0xf, 0xf, false);
  hi = __builtin_amdgcn_update_dpp(hi, hi, CTRL, 0xf, 0xf, false);
  return ((unsigned long long)(unsigned int)hi << 32) | (unsigned int)lo;
}

// Wave(64)-wide float max via DPP (VALU pipe). Result broadcast via readlane 63.
__device__ __forceinline__ float wave_max_f32_dpp(float v) {
  int x = __float_as_int(v);
#define STEP(ctrl)                                                        \
  {                                                                       \
    int t = __builtin_amdgcn_update_dpp(x, x, ctrl, 0xf, 0xf, false);     \
    v = fmaxf(v, __int_as_float(t));                                      \
    x = __float_as_int(v);                                                \
  }
  STEP(0x111)
  STEP(0x112)
  STEP(0x114)
  STEP(0x118)
  STEP(0x142)
  STEP(0x143)
#undef STEP
  return __int_as_float(__builtin_amdgcn_readlane(x, 63));
}

// ---------------------------------------------------------------------------
// FPS r4: ONE WAVE per batch (blocks 0..7, lanes own contiguous 64-point
// runs, all coords+dist in registers ~290 VGPR at 1 wave/SIMD). Removes the
// 4-wave barrier + keyp LDS round-trip + u64 merge from the per-step serial
// chain; only remaining per-step LDS latency is the broadcast sp[widx] read.
// Tie-break identical to validated rounds: descending equality scan gives
// smallest in-lane index at max; ballot lowest lane = smallest global index
// (contiguous ownership). Arithmetic: contract(off) pk sub/mul/add + IEEE
// elementwise min/max — bit-identical to r2.
// Blocks 8..519 transpose feature [b][c][n] -> featT [b][n][c].
// ---------------------------------------------------------------------------
__global__ __launch_bounds__(256, 1) void fps_kernel(const float* __restrict__ xyz,
                                                     int* __restrict__ fps_idx,
                                                     float* __restrict__ nxyz,
                                                     float* __restrict__ out0,
                                                     const float* __restrict__ feature,
                                                     float* __restrict__ featT) {
#pragma clang fp contract(off)
  const int tid = threadIdx.x;
  __shared__ __align__(16) float4 sp[N_];    // 64 KB coord mirror / transpose tile
  __shared__ int si[S_];
  if (blockIdx.x >= 8) {
    // ---- fused transpose (validated r7 transpose_feat logic, 256 thr) ----
    const int blk = blockIdx.x - 8;
    const int b = blk >> 6, n0 = (blk & 63) * 64;
    float* tile = (float*)sp;  // 64*65 floats = 16.6 KB
#pragma unroll
    for (int i = 0; i < 16; i++) {
      int c = i * 4 + (tid >> 6), nl = tid & 63;
      tile[c * 65 + nl] = feature[((size_t)b * 64 + c) * N_ + n0 + nl];
    }
    __syncthreads();
#pragma unroll
    for (int i = 0; i < 16; i++) {
      int nl = i * 4 + (tid >> 6), c = tid & 63;
      featT[((size_t)b * N_ + n0 + nl) * 64 + c] = tile[c * 65 + nl];
    }
    return;
  }
  if (tid >= 64) return;  // single-wave FPS path; no __syncthreads below
  const int b = blockIdx.x;
  const float* xb = xyz + (size_t)b * 3 * N_;
  const float4* xv = (const float4*)xb;
  f32x2 px[32], py[32], pz[32], dd[32];
#pragma unroll
  for (int q = 0; q < 16; q++) {
    float4 X = xv[16 * tid + q];
    float4 Y = xv[1024 + 16 * tid + q];
    float4 Z = xv[2048 + 16 * tid + q];
    px[2 * q] = (f32x2){X.x, X.y};  px[2 * q + 1] = (f32x2){X.z, X.w};
    py[2 * q] = (f32x2){Y.x, Y.y};  py[2 * q + 1] = (f32x2){Y.z, Y.w};
    pz[2 * q] = (f32x2){Z.x, Z.y};  pz[2 * q + 1] = (f32x2){Z.z, Z.w};
    sp[64 * tid + 4 * q + 0] = make_float4(X.x, Y.x, Z.x, 0.f);
    sp[64 * tid + 4 * q + 1] = make_float4(X.y, Y.y, Z.y, 0.f);
    sp[64 * tid + 4 * q + 2] = make_float4(X.z, Y.z, Z.z, 0.f);
    sp[64 * tid + 4 * q + 3] = make_float4(X.w, Y.w, Z.w, 0.f);
  }
#pragma unroll
  for (int j = 0; j < 32; j++) dd[j] = (f32x2){1e10f, 1e10f};
  if (tid == 0) si[0] = 0;
  // centroid 0 = point 0 (lane 0's first coords) — no LDS needed
  float cx = __int_as_float(__builtin_amdgcn_readlane(__float_as_int(px[0].x), 0));
  float cy = __int_as_float(__builtin_amdgcn_readlane(__float_as_int(py[0].x), 0));
  float cz = __int_as_float(__builtin_amdgcn_readlane(__float_as_int(pz[0].x), 0));
  for (int s = 1; s < S_; s++) {
    const f32x2 c2x = {cx, cx}, c2y = {cy, cy}, c2z = {cz, cz};
    // --- packed dist update (exact: pk lanes are independent IEEE ops,
    //     same op order (dx*dx + dy*dy) + dz*dz as validated rounds) ---
#pragma unroll
    for (int j = 0; j < 32; j++) {
      f32x2 dx = px[j] - c2x;
      f32x2 dy = py[j] - c2y;
      f32x2 dz = pz[j] - c2z;
      f32x2 d = (dx * dx + dy * dy) + dz * dz;
      dd[j] = __builtin_elementwise_min(dd[j], d);
    }
    // --- local max via packed fmax tree (order-independent, exact) ---
    f32x2 m16[16], m8[8], m4[4], m2[2];
#pragma unroll
    for (int j = 0; j < 16; j++) m16[j] = __builtin_elementwise_max(dd[2 * j], dd[2 * j + 1]);
#pragma unroll
    for (int j = 0; j < 8; j++) m8[j] = __builtin_elementwise_max(m16[2 * j], m16[2 * j + 1]);
#pragma unroll
    for (int j = 0; j < 4; j++) m4[j] = __builtin_elementwise_max(m8[2 * j], m8[2 * j + 1]);
#pragma unroll
    for (int j = 0; j < 2; j++) m2[j] = __builtin_elementwise_max(m4[2 * j], m4[2 * j + 1]);
    f32x2 m1 = __builtin_elementwise_max(m2[0], m2[1]);
    float best = fmaxf(m1.x, m1.y);
    // --- local argmax: descending equality scan (.y before .x) -> smallest
    //     in-lane index with dist == max; same tie-break as validated scan ---
    int bi = 64 * tid;
#pragma unroll
    for (int j = 31; j >= 0; j--) {
      if (dd[j].y == best) bi = 64 * tid + 2 * j + 1;
      if (dd[j].x == best) bi = 64 * tid + 2 * j;
    }
    float wmax = wave_max_f32_dpp(best);
    unsigned long long mm = __ballot(best == wmax);
    int l = __ffsll(mm) - 1;
    int widx = __builtin_amdgcn_readlane(bi, l);
    if (tid == 0) si[s] = widx;
    float4 c = sp[widx];  // broadcast read, only per-step LDS latency
    cx = c.x; cy = c.y; cz = c.z;
  }
  for (int e = tid; e < S_; e += 64) {
    int n = si[e];
    fps_idx[b * S_ + e] = n;
    float4 c = sp[n];
    nxyz[(size_t)(b * S_ + e) * 3 + 0] = c.x;
    nxyz[(size_t)(b * S_ + e) * 3 + 1] = c.y;
    nxyz[(size_t)(b * S_ + e) * 3 + 2] = c.z;
    out0[(size_t)b * 3 * S_ + e] = c.x;
    out0[(size_t)b * 3 * S_ + S_ + e] = c.y;
    out0[(size_t)b * 3 * S_ + 2 * S_ + e] = c.z;
  }
}

// ---------------------------------------------------------------------------
// kNN (validated r4/r7 selection logic — unchanged). r2: distance-init loop
// packed into f32x2 pairs (same expanded-form op order, exact). Blocks >= 8192
// perform the fused anchor-feature gather from featT.
// ---------------------------------------------------------------------------
__global__ __launch_bounds__(256) void knn_kernel(const float* __restrict__ xyz,
                                                  const float* __restrict__ nxyz,
                                                  int* __restrict__ knn,
                                                  const float* __restrict__ featT,
                                                  const int* __restrict__ fps_i,
                                                  float* __restrict__ nfeat) {
#pragma clang fp contract(off)
  const int bs = blockIdx.x, tid = threadIdx.x;
  if (bs >= 8192) {
    int e = (bs - 8192) * 256 + tid;  // < B*S*D
    int bsx = e >> 6, c = e & 63;
    int bq = bsx >> 10;
    int n = fps_i[bsx];
    nfeat[e] = featT[((size_t)bq * N_ + n) * 64 + c];
    return;
  }
  const int b = bs >> 10;
  const float* xb = xyz + (size_t)b * 3 * N_;
  const float cx = nxyz[(size_t)bs * 3], cy = nxyz[(size_t)bs * 3 + 1], cz = nxyz[(size_t)bs * 3 + 2];
  const float cn = (cx * cx + cy * cy) + cz * cz;
  const f32x2 c2x = {cx, cx}, c2y = {cy, cy}, c2z = {cz, cz};
  const f32x2 c2n = {cn, cn}, two = {2.0f, 2.0f};
  float d[16];
#pragma unroll
  for (int j = 0; j < 8; j++) {
    int n0 = (2 * j) * 256 + tid, n1 = n0 + 256;
    f32x2 px = {xb[n0], xb[n1]};
    f32x2 py = {xb[N_ + n0], xb[N_ + n1]};
    f32x2 pz = {xb[2 * N_ + n0], xb[2 * N_ + n1]};
    f32x2 pn = (px * px + py * py) + pz * pz;
    f32x2 dot = (c2x * px + c2y * py) + c2z * pz;
    f32x2 dd = (c2n + pn) - two * dot;
    d[2 * j] = dd.x;
    d[2 * j + 1] = dd.y;
  }
  float mv = FLT_MAX;
  int mi = tid;
#pragma unroll
  for (int i = 0; i < 16; i++)
    if (d[i] < mv) { mv = d[i]; mi = i * 256 + tid; }
  __shared__ unsigned long long keyp[2][4];
  __shared__ int skk[K_];
  const int wav = tid >> 6, lane = tid & 63;
  for (int j = 0; j < K_; j++) {
    unsigned int u = __float_as_uint(mv);
    u ^= ((unsigned int)((int)u >> 31) | 0x80000000u);
    unsigned long long key = ((unsigned long long)u << 32) | (unsigned int)mi;
#pragma unroll
    for (int off = 32; off >= 1; off >>= 1) {
      unsigned long long ok = __shfl_xor(key, off);
      if (ok < key) key = ok;
    }
    if (lane == 0) keyp[j & 1][wav] = key;
    __syncthreads();
    unsigned long long kmin = keyp[j & 1][0];
#pragma unroll
    for (int w = 1; w < 4; w++) {
      unsigned long long k2 = keyp[j & 1][w];
      if (k2 < kmin) kmin = k2;
    }
    int g = (int)(kmin & 0xffffffffull);
    if (tid == 0) skk[j] = g;
    if ((g & 255) == tid) {
      int sl = g >> 8;
#pragma unroll
      for (int i = 0; i < 16; i++)
        if (i == sl) d[i] = FLT_MAX;
      mv = FLT_MAX; mi = tid;
#pragma unroll
      for (int i = 0; i < 16; i++)
        if (d[i] < mv) { mv = d[i]; mi = i * 256 + tid; }
    }
  }
  __syncthreads();
  if (tid < K_) knn[(size_t)bs * K_ + tid] = skk[tid];
}

// ===========================================================================
// ============ FALLBACK (r6) kernels — used when ws is small ================
// ===========================================================================
__global__ __launch_bounds__(256) void gather_nf(const float* __restrict__ feature,
                                                 const int* __restrict__ fps_i,
                                                 float* __restrict__ nfeat) {
  int e = blockIdx.x * 256 + threadIdx.x;
  int b = e >> 16, rem = e & 65535;
  int s = rem >> 6, c = rem & 63;
  int n = fps_i[b * S_ + s];
  nfeat[e] = feature[((size_t)b * 64 + c) * N_ + n];
}

__global__ __launch_bounds__(256) void std_partial(const float* __restrict__ feature,
                                                   const float* __restrict__ xyz,
                                                   const float* __restrict__ nxyz,
                                                   const float* __restrict__ nfeat,
                                                   const int* __restrict__ knn,
                                                   float* __restrict__ outp) {
  const int blk = blockIdx.x, tid = threadIdx.x;
  const int b = blk >> 6, chunk = blk & 63;
  float s = 0.f, q = 0.f;
  for (int e = tid; e < 16 * K_ * 67; e += 256) {
    int so = e / (K_ * 67);
    int rem = e - so * (K_ * 67);
    int kk = rem / 67;
    int c = rem - kk * 67;
    int bs = b * S_ + chunk * 16 + so;
    int n = knn[(size_t)bs * K_ + kk];
    float raw = (c < 64) ? feature[((size_t)b * 64 + c) * N_ + n]
                         : xyz[((size_t)b * 3 + (c - 64)) * N_ + n];
    float anc = (c < 64) ? nfeat[(size_t)bs * 64 + c]
                         : nxyz[(size_t)bs * 3 + (c - 64)];
    float dd = raw - anc;
    s += dd; q += dd * dd;
  }
#pragma unroll
  for (int off = 32; off >= 1; off >>= 1) { s += __shfl_xor(s, off); q += __shfl_xor(q, off); }
  __shared__ float rs[4], rq[4];
  if ((tid & 63) == 0) { rs[tid >> 6] = s; rq[tid >> 6] = q; }
  __syncthreads();
  if (tid == 0) {
    outp[blk * 2] = rs[0] + rs[1] + rs[2] + rs[3];
    outp[blk * 2 + 1] = rq[0] + rq[1] + rq[2] + rq[3];
  }
}

__global__ void std_final(const float* __restrict__ part, float* __restrict__ invstd) {
  int b = threadIdx.x;
  if (b < B_) {
    double s = 0.0, q = 0.0;
    for (int i = 0; i < 64; i++) {
      s += (double)part[(b * 64 + i) * 2];
      q += (double)part[(b * 64 + i) * 2 + 1];
    }
    const double n = (double)(S_ * K_ * 67);
    double var = (q - s * s / n) / (n - 1.0);
    invstd[b] = (float)(1.0 / (sqrt(var) + 1e-5));
  }
}

template <int MODE>
__global__ __launch_bounds__(256, 2) void mlp_kernel(
    const float* __restrict__ feature, const float* __restrict__ xyz,
    const float* __restrict__ nxyz, const float* __restrict__ nfeat,
    const int* __restrict__ knn, const float* __restrict__ invstd,
    const float* __restrict__ alpha, const float* __restrict__ beta,
    const float* __restrict__ w_tr, const float* __restrict__ b_tr,
    const float* __restrict__ w1, const float* __restrict__ b1,
    const float* __restrict__ w2, const float* __restrict__ b2,
    const float* __restrict__ bn_tr, const float* __restrict__ bn_1,
    float* __restrict__ bnpart, float* __restrict__ out1) {
  __shared__ __align__(16) float pool[15556];
  float* Wt = pool;
  float* xin = pool + 8516;
  float* ub = xin;
  float* tb = pool + 8516 + 4192;
  float* part = pool + 8516 + 4192 + 2304;
  int* sknn = (int*)(part + 512);
  const int bs = blockIdx.x, tid = threadIdx.x;
  const int b = bs >> 10, s = bs & 1023;
  if (tid < K_) sknn[tid] = knn[(size_t)bs * K_ + tid];
  for (int e = tid; e < 64 * 131; e += 256) {
    int o = e / 131, c = e - o * 131;
    Wt[c * 65 + o] = w_tr[e];
  }
  __syncthreads();
  const float inv = invstd[b];
  for (int e = tid; e < CIN_ * K_; e += 256) {
    int c = e >> 5, kk = e & 31;
    float v;
    if (c < 67) {
      int n = sknn[kk];
      float raw = (c < 64) ? feature[((size_t)b * 64 + c) * N_ + n]
                           : xyz[((size_t)b * 3 + (c - 64)) * N_ + n];
      float anc = (c < 64) ? nfeat[(size_t)bs * 64 + c]
                           : nxyz[(size_t)bs * 3 + (c - 64)];
      v = alpha[c] * ((raw - anc) * inv) + beta[c];
    } else {
      v = nfeat[(size_t)bs * 64 + (c - 67)];
    }
    xin[e] = v;
  }
  __syncthreads();
  const int o = tid & 63, kkb = (tid >> 6) * 8;
  float acc[8];
  {
    float bv = b_tr[o];
#pragma unroll
    for (int j = 0; j < 8; j++) acc[j] = bv;
  }
  for (int c = 0; c < CIN_; c++) {
    float w = Wt[c * 65 + o];
    const float4 xa = *(const float4*)(xin + c * 32 + kkb);
    const float4 xb4 = *(const float4*)(xin + c * 32 + kkb + 4);
    acc[0] += w * xa.x; acc[1] += w * xa.y; acc[2] += w * xa.z; acc[3] += w * xa.w;
    acc[4] += w * xb4.x; acc[5] += w * xb4.y; acc[6] += w * xb4.z; acc[7] += w * xb4.w;
  }
  if (MODE == 0) {
    float s8 = 0.f, q8 = 0.f;
#pragma unroll
    for (int j = 0; j < 8; j++) { s8 += acc[j]; q8 += acc[j] * acc[j]; }
    part[(tid >> 6) * 64 + o] = s8;
    part[256 + (tid >> 6) * 64 + o] = q8;
    __syncthreads();
    if (tid < 64) {
      float ss = 0.f, qq = 0.f;
      for (int g = 0; g < 4; g++) { ss += part[g * 64 + tid]; qq += part[256 + g * 64 + tid]; }
      bnpart[(size_t)bs * 128 + tid] = ss;
      bnpart[(size_t)bs * 128 + 64 + tid] = qq;
    }
    return;
  }
  float tv[8];
  {
    float sc = bn_tr[o], sh = bn_tr[64 + o];
#pragma unroll
    for (int j = 0; j < 8; j++) {
      tv[j] = fmaxf(fmaf(sc, acc[j], sh), 0.f);
      tb[o * 36 + kkb + j] = tv[j];
    }
  }
  __syncthreads();
  for (int e = tid; e < 64 * 64; e += 256) {
    int oo = e >> 6, c = e & 63;
    Wt[c * 65 + oo] = w1[e];
  }
  __syncthreads();
  float acc2[8];
  {
    float bv = b1[o];
#pragma unroll
    for (int j = 0; j < 8; j++) acc2[j] = bv;
  }
  for (int c = 0; c < 64; c++) {
    float w = Wt[c * 65 + o];
    const float4 ta = *(const float4*)(tb + c * 36 + kkb);
    const float4 ta2 = *(const float4*)(tb + c * 36 + kkb + 4);
    acc2[0] += w * ta.x; acc2[1] += w * ta.y; acc2[2] += w * ta.z; acc2[3] += w * ta.w;
    acc2[4] += w * ta2.x; acc2[5] += w * ta2.y; acc2[6] += w * ta2.z; acc2[7] += w * ta2.w;
  }
  if (MODE == 1) {
    float s8 = 0.f, q8 = 0.f;
#pragma unroll
    for (int j = 0; j < 8; j++) { s8 += acc2[j]; q8 += acc2[j] * acc2[j]; }
    part[(tid >> 6) * 64 + o] = s8;
    part[256 + (tid >> 6) * 64 + o] = q8;
    __syncthreads();
    if (tid < 64) {
      float ss = 0.f, qq = 0.f;
      for (int g = 0; g < 4; g++) { ss += part[g * 64 + tid]; qq += part[256 + g * 64 + tid]; }
      bnpart[(size_t)bs * 128 + tid] = ss;
      bnpart[(size_t)bs * 128 + 64 + tid] = qq;
    }
    return;
  }
  {
    float sc = bn_1[o], sh = bn_1[64 + o];
#pragma unroll
    for (int j = 0; j < 8; j++) ub[o * 36 + kkb + j] = fmaxf(fmaf(sc, acc2[j], sh), 0.f);
  }
  __syncthreads();
  for (int e = tid; e < 64 * 64; e += 256) {
    int oo = e >> 6, c = e & 63;
    Wt[c * 65 + oo] = w2[e];
  }
  __syncthreads();
  float acc3[8];
  {
    float bv = b2[o];
#pragma unroll
    for (int j = 0; j < 8; j++) acc3[j] = bv;
  }
  for (int c = 0; c < 64; c++) {
    float w = Wt[c * 65 + o];
    const float4 ua = *(const float4*)(ub + c * 36 + kkb);
    const float4 ua2 = *(const float4*)(ub + c * 36 + kkb + 4);
    acc3[0] += w * ua.x; acc3[1] += w * ua.y; acc3[2] += w * ua.z; acc3[3] += w * ua.w;
    acc3[4] += w * ua2.x; acc3[5] += w * ua2.y; acc3[6] += w * ua2.z; acc3[7] += w * ua2.w;
  }
  float m = 0.f;
#pragma unroll
  for (int j = 0; j < 8; j++) m = fmaxf(m, fmaxf(acc3[j] + tv[j], 0.f));
  part[(tid >> 6) * 64 + o] = m;
  __syncthreads();
  if (tid < 64) {
    float mm = part[tid];
    for (int g = 1; g < 4; g++) mm = fmaxf(mm, part[g * 64 + tid]);
    out1[((size_t)b * 64 + tid) * S_ + s] = mm;
  }
}

// ---------------------------------------------------------------------------
// BN finalize (shared by both paths).
// ---------------------------------------------------------------------------
__global__ __launch_bounds__(256) void bn_finalize(const float* __restrict__ part,
                                                   const float* __restrict__ g,
                                                   const float* __restrict__ be,
                                                   float* __restrict__ bnout) {
  const int ch = blockIdx.x, tid = threadIdx.x;
  double s = 0.0, q = 0.0;
  for (int i = tid; i < B_ * S_; i += 256) {
    s += (double)part[(size_t)i * 128 + ch];
    q += (double)part[(size_t)i * 128 + 64 + ch];
  }
#pragma unroll
  for (int off = 32; off >= 1; off >>= 1) { s += __shfl_xor(s, off); q += __shfl_xor(q, off); }
  __shared__ double ls[4], lq[4];
  if ((tid & 63) == 0) { ls[tid >> 6] = s; lq[tid >> 6] = q; }
  __syncthreads();
  if (tid == 0) {
    double Ssum = ls[0] + ls[1] + ls[2] + ls[3];
    double Qsum = lq[0] + lq[1] + lq[2] + lq[3];
    const double n = (double)(B_ * S_ * K_);
    double mu = Ssum / n;
    double var = Qsum / n - mu * mu;
    double sc = (double)g[ch] / sqrt(var + 1e-5);
    bnout[ch] = (float)sc;
    bnout[64 + ch] = (float)((double)be[ch] - mu * sc);
  }
}

// ===========================================================================
// ================== CACHE-PATH kernels (large workspace) ===================
// ===========================================================================

// Fused diff computation + std partials. 1024 blocks x 8 groups.
__global__ __launch_bounds__(256) void prep_kernel(const float* __restrict__ featT,
                                                   const float* __restrict__ xyz,
                                                   const float* __restrict__ nxyz,
                                                   const float* __restrict__ nfeat,
                                                   const int* __restrict__ knn,
                                                   float* __restrict__ dcache,
                                                   float* __restrict__ outp) {
  const int blk = blockIdx.x, tid = threadIdx.x;
  __shared__ int sk[32];
  float s = 0.f, q = 0.f;
  const int c = tid & 63, qd = tid >> 6;
  for (int g = 0; g < 8; g++) {
    const int bs = blk * 8 + g, b = bs >> 10;
    if (tid < 32) sk[tid] = knn[(size_t)bs * K_ + tid];
    __syncthreads();
    float anc = nfeat[(size_t)bs * 64 + c];
#pragma unroll
    for (int it = 0; it < 8; it++) {
      int kk = it * 4 + qd;
      int n = sk[kk];
      float dd = featT[((size_t)b * N_ + n) * 64 + c] - anc;
      s += dd; q += dd * dd;
      dcache[((size_t)bs * 32 + kk) * 68 + c] = dd;
    }
    if (tid < 96) {
      int c3 = tid >> 5, kk = tid & 31;
      int n = sk[kk];
      float dd = xyz[((size_t)b * 3 + c3) * N_ + n] - nxyz[(size_t)bs * 3 + c3];
      s += dd; q += dd * dd;
      dcache[((size_t)bs * 32 + kk) * 68 + 64 + c3] = dd;
    }
    __syncthreads();
  }
#pragma unroll
  for (int off = 32; off >= 1; off >>= 1) { s += __shfl_xor(s, off); q += __shfl_xor(q, off); }
  __shared__ float rs[4], rq[4];
  if ((tid & 63) == 0) { rs[tid >> 6] = s; rq[tid >> 6] = q; }
  __syncthreads();
  if (tid == 0) {
    outp[blk * 2] = rs[0] + rs[1] + rs[2] + rs[3];
    outp[blk * 2 + 1] = rq[0] + rq[1] + rq[2] + rq[3];
  }
}

__global__ void std_final_c(const float* __restrict__ part, float* __restrict__ invstd) {
  int b = threadIdx.x;
  if (b < B_) {
    double s = 0.0, q = 0.0;
    for (int i = 0; i < 128; i++) {
      s += (double)part[(b * 128 + i) * 2];
      q += (double)part[(b * 128 + i) * 2 + 1];
    }
    const double n = (double)(S_ * K_ * 67);
    double var = (q - s * s / n) / (n - 1.0);
    invstd[b] = (float)(1.0 / (sqrt(var) + 1e-5));
  }
}

// MLP stage 0: xin from dcache (coalesced), conv_tr, stats + tcache store.
__global__ __launch_bounds__(256, 2) void mlp0c(
    const float* __restrict__ dcache, const float* __restrict__ nfeat,
    const float* __restrict__ invstd,
    const float* __restrict__ alpha, const float* __restrict__ beta,
    const float* __restrict__ w_tr, const float* __restrict__ b_tr,
    float* __restrict__ bnpart, float* __restrict__ tcache) {
  __shared__ __align__(16) float pool[13220];
  float* Wt = pool;
  float* xin = pool + 8516;
  float* part = pool + 8516 + 4192;
  const int bs = blockIdx.x, tid = threadIdx.x;
  const int b = bs >> 10;
  for (int e = tid; e < 64 * 131; e += 256) {
    int o = e / 131, c = e - o * 131;
    Wt[c * 65 + o] = w_tr[e];
  }
  const float inv = invstd[b];
  {
    const int c = tid & 63, qd = tid >> 6;
    float al = alpha[c], bev = beta[c];
#pragma unroll
    for (int it = 0; it < 8; it++) {
      int kk = it * 4 + qd;
      xin[c * 32 + kk] = al * (dcache[((size_t)bs * 32 + kk) * 68 + c] * inv) + bev;
    }
    if (tid < 96) {
      int c3 = 64 + (tid >> 5), kk = tid & 31;
      xin[c3 * 32 + kk] =
          alpha[c3] * (dcache[((size_t)bs * 32 + kk) * 68 + c3] * inv) + beta[c3];
    }
    for (int e = tid; e < 2048; e += 256) {
      int cc = 67 + (e >> 5), kk = e & 31;
      xin[cc * 32 + kk] = nfeat[(size_t)bs * 64 + (e >> 5)];
    }
  }
  __syncthreads();
  const int o = tid & 63, kkb = (tid >> 6) * 8;
  float acc[8];
  {
    float bv = b_tr[o];
#pragma unroll
    for (int j = 0; j < 8; j++) acc[j] = bv;
  }
  for (int c = 0; c < CIN_; c++) {
    float w = Wt[c * 65 + o];
    const float4 xa = *(const float4*)(xin + c * 32 + kkb);
    const float4 xb4 = *(const float4*)(xin + c * 32 + kkb + 4);
    acc[0] += w * xa.x; acc[1] += w * xa.y; acc[2] += w * xa.z; acc[3] += w * xa.w;
    acc[4] += w * xb4.x; acc[5] += w * xb4.y; acc[6] += w * xb4.z; acc[7] += w * xb4.w;
  }
  {
    float4* tp = (float4*)(tcache + ((size_t)bs * 64 + o) * 32 + kkb);
    tp[0] = make_float4(acc[0], acc[1], acc[2], acc[3]);
    tp[1] = make_float4(acc[4], acc[5], acc[6], acc[7]);
  }
  float s8 = 0.f, q8 = 0.f;
#pragma unroll
  for (int j = 0; j < 8; j++) { s8 += acc[j]; q8 += acc[j] * acc[j]; }
  part[(tid >> 6) * 64 + o] = s8;
  part[256 + (tid >> 6) * 64 + o] = q8;
  __syncthreads();
  if (tid < 64) {
    float ss = 0.f, qq = 0.f;
    for (int g = 0; g < 4; g++) { ss += part[g * 64 + tid]; qq += part[256 + g * 64 + tid]; }
    bnpart[(size_t)bs * 128 + tid] = ss;
    bnpart[(size_t)bs * 128 + 64 + tid] = qq;
  }
}

// MLP stage 1: t = bn+relu(tcache); conv1; stats + ucache store.
__global__ __launch_bounds__(256, 3) void mlp1c(
    const float* __restrict__ tcache, const float* __restrict__ bn_tr,
    const float* __restrict__ w1, const float* __restrict__ b1,
    float* __restrict__ bnpart, float* __restrict__ ucache) {
  __shared__ __align__(16) float pool[6976];
  float* Wt = pool;
  float* tb = pool + 4160;
  float* part = pool + 4160 + 2304;
  const int bs = blockIdx.x, tid = threadIdx.x;
  const int o = tid & 63, kkb = (tid >> 6) * 8;
  for (int e = tid; e < 64 * 64; e += 256) {
    int oo = e >> 6, c = e & 63;
    Wt[c * 65 + oo] = w1[e];
  }
  float t[8];
  {
    const float4* tp = (const float4*)(tcache + ((size_t)bs * 64 + o) * 32 + kkb);
    float4 a = tp[0], b4 = tp[1];
    t[0] = a.x; t[1] = a.y; t[2] = a.z; t[3] = a.w;
    t[4] = b4.x; t[5] = b4.y; t[6] = b4.z; t[7] = b4.w;
  }
  {
    float sc = bn_tr[o], sh = bn_tr[64 + o];
#pragma unroll
    for (int j = 0; j < 8; j++) tb[o * 36 + kkb + j] = fmaxf(fmaf(sc, t[j], sh), 0.f);
  }
  __syncthreads();
  float acc2[8];
  {
    float bv = b1[o];
#pragma unroll
    for (int j = 0; j < 8; j++) acc2[j] = bv;
  }
  for (int c = 0; c < 64; c++) {
    float w = Wt[c * 65 + o];
    const float4 ta = *(const float4*)(tb + c * 36 + kkb);
    const float4 ta2 = *(const float4*)(tb + c * 36 + kkb + 4);
    acc2[0] += w * ta.x; acc2[1] += w * ta.y; acc2[2] += w * ta.z; acc2[3] += w * ta.w;
    acc2[4] += w * ta2.x; acc2[5] += w * ta2.y; acc2[6] += w * ta2.z; acc2[7] += w * ta2.w;
  }
  {
    float4* up = (float4*)(ucache + ((size_t)bs * 64 + o) * 32 + kkb);
    up[0] = make_float4(acc2[0], acc2[1], acc2[2], acc2[3]);
    up[1] = make_float4(acc2[4], acc2[5], acc2[6], acc2[7]);
  }
  float s8 = 0.f, q8 = 0.f;
#pragma unroll
  for (int j = 0; j < 8; j++) { s8 += acc2[j]; q8 += acc2[j] * acc2[j]; }
  part[(tid >> 6) * 64 + o] = s8;
  part[256 + (tid >> 6) * 64 + o] = q8;
  __syncthreads();
  if (tid < 64) {
    float ss = 0.f, qq = 0.f;
    for (int g = 0; g < 4; g++) { ss += part[g * 64 + tid]; qq += part[256 + g * 64 + tid]; }
    bnpart[(size_t)bs * 128 + tid] = ss;
    bnpart[(size_t)bs * 128 + 64 + tid] = qq;
  }
}

// MLP stage 2: u = bn+relu(ucache); conv2; residual with bn+relu(tcache); max.
__global__ __launch_bounds__(256, 3) void mlp2c(
    const float* __restrict__ tcache, const float* __restrict__ ucache,
    const float* __restrict__ bn_tr, const float* __restrict__ bn_1,
    const float* __restrict__ w2, const float* __restrict__ b2,
    float* __restrict__ out1) {
  __shared__ __align__(16) float pool[6976];
  float* Wt = pool;
  float* ub = pool + 4160;
  float* part = pool + 4160 + 2304;
  const int bs = blockIdx.x, tid = threadIdx.x;
  const int b = bs >> 10, s = bs & 1023;
  const int o = tid & 63, kkb = (tid >> 6) * 8;
  for (int e = tid; e < 64 * 64; e += 256) {
    int oo = e >> 6, c = e & 63;
    Wt[c * 65 + oo] = w2[e];
  }
  {
    const float4* up = (const float4*)(ucache + ((size_t)bs * 64 + o) * 32 + kkb);
    float4 a = up[0], b4 = up[1];
    float u[8] = {a.x, a.y, a.z, a.w, b4.x, b4.y, b4.z, b4.w};
    float sc = bn_1[o], sh = bn_1[64 + o];
#pragma unroll
    for (int j = 0; j < 8; j++) ub[o * 36 + kkb + j] = fmaxf(fmaf(sc, u[j], sh), 0.f);
  }
  __syncthreads();
  float acc3[8];
  {
    float bv = b2[o];
#pragma unroll
    for (int j = 0; j < 8; j++) acc3[j] = bv;
  }
  for (int c = 0; c < 64; c++) {
    float w = Wt[c * 65 + o];
    const float4 ua = *(const float4*)(ub + c * 36 + kkb);
    const float4 ua2 = *(const float4*)(ub + c * 36 + kkb + 4);
    acc3[0] += w * ua.x; acc3[1] += w * ua.y; acc3[2] += w * ua.z; acc3[3] += w * ua.w;
    acc3[4] += w * ua2.x; acc3[5] += w * ua2.y; acc3[6] += w * ua2.z; acc3[7] += w * ua2.w;
  }
  float tv[8];
  {
    const float4* tp = (const float4*)(tcache + ((size_t)bs * 64 + o) * 32 + kkb);
    float4 a = tp[0], b4 = tp[1];
    float t[8] = {a.x, a.y, a.z, a.w, b4.x, b4.y, b4.z, b4.w};
    float sc = bn_tr[o], sh = bn_tr[64 + o];
#pragma unroll
    for (int j = 0; j < 8; j++) tv[j] = fmaxf(fmaf(sc, t[j], sh), 0.f);
  }
  float m = 0.f;
#pragma unroll
  for (int j = 0; j < 8; j++) m = fmaxf(m, fmaxf(acc3[j] + tv[j], 0.f));
  part[(tid >> 6) * 64 + o] = m;
  __syncthreads();
  if (tid < 64) {
    float mm = part[tid];
    for (int g = 1; g < 4; g++) mm = fmaxf(mm, part[g * 64 + tid]);
    out1[((size_t)b * 64 + tid) * S_ + s] = mm;
  }
}

// ---------------------------------------------------------------------------
extern "C" void kernel_launch(void* const* d_in, const int* in_sizes, int n_in,
                              void* d_out, int out_size, void* d_ws, size_t ws_size,
                              hipStream_t stream) {
  const float* xyz = (const float*)d_in[0];
  const float* feature = (const float*)d_in[1];
  const float* alpha = (const float*)d_in[2];
  const float* beta = (const float*)d_in[3];
  const float* w_tr = (const float*)d_in[4];
  const float* b_tr = (const float*)d_in[5];
  const float* g_tr = (const float*)d_in[6];
  const float* be_tr = (const float*)d_in[7];
  const float* w1 = (const float*)d_in[8];
  const float* b1 = (const float*)d_in[9];
  const float* g1 = (const float*)d_in[10];
  const float* be1 = (const float*)d_in[11];
  const float* w2 = (const float*)d_in[12];
  const float* b2 = (const float*)d_in[13];

  char* ws = (char*)d_ws;
  int* fps_i = (int*)(ws);                      // 32768 B
  float* nxyz = (float*)(ws + 32768);           // 98304 B
  float* nfeat = (float*)(ws + 131072);         // 2097152 B
  int* knn = (int*)(ws + 2228224);              // 1048576 B
  float* stdpart = (float*)(ws + 3276800);      // 4096 B (fallback)
  float* invstd = (float*)(ws + 3280896);       // 64 B
  float* bn_tr = (float*)(ws + 3280960);        // 512 B
  float* bn_1 = (float*)(ws + 3281472);         // 512 B
  float* bnpart = (float*)(ws + 3281984);       // 4194304 B -> end 7476288
  float* featT = (float*)(ws + 7476288);        // 8388608 B
  float* dcache = (float*)(ws + 15864896);      // 71303168 B
  float* tcache = (float*)(ws + 87168064);      // 67108864 B
  float* ucache = (float*)(ws + 154276928);     // 67108864 B
  float* stdpart_c = (float*)(ws + 221385792);  // 8192 B -> total 221393984

  float* out0 = (float*)d_out;
  float* out1 = out0 + B_ * 3 * S_;

  const bool big = (ws_size >= 221393984ull);

  if (big) {
    // fps blocks 0..7 (1-wave FPS) + 512 fused-transpose blocks
    fps_kernel<<<8 + 512, 256, 0, stream>>>(xyz, fps_i, nxyz, out0, feature, featT);
    // knn blocks 0..8191 + 2048 fused anchor-gather blocks
    knn_kernel<<<8192 + 2048, 256, 0, stream>>>(xyz, nxyz, knn, featT, fps_i, nfeat);
    prep_kernel<<<1024, 256, 0, stream>>>(featT, xyz, nxyz, nfeat, knn, dcache, stdpart_c);
    std_final_c<<<1, 64, 0, stream>>>(stdpart_c, invstd);
    mlp0c<<<B_ * S_, 256, 0, stream>>>(dcache, nfeat, invstd, alpha, beta, w_tr, b_tr,
                                       bnpart, tcache);
    bn_finalize<<<64, 256, 0, stream>>>(bnpart, g_tr, be_tr, bn_tr);
    mlp1c<<<B_ * S_, 256, 0, stream>>>(tcache, bn_tr, w1, b1, bnpart, ucache);
    bn_finalize<<<64, 256, 0, stream>>>(bnpart, g1, be1, bn_1);
    mlp2c<<<B_ * S_, 256, 0, stream>>>(tcache, ucache, bn_tr, bn_1, w2, b2, out1);
  } else {
    fps_kernel<<<8, 256, 0, stream>>>(xyz, fps_i, nxyz, out0, feature, featT);
    gather_nf<<<(B_ * S_ * D_) / 256, 256, 0, stream>>>(feature, fps_i, nfeat);
    knn_kernel<<<8192, 256, 0, stream>>>(xyz, nxyz, knn, nullptr, nullptr, nullptr);
    std_partial<<<B_ * 64, 256, 0, stream>>>(feature, xyz, nxyz, nfeat, knn, stdpart);
    std_final<<<1, 64, 0, stream>>>(stdpart, invstd);
    mlp_kernel<0><<<B_ * S_, 256, 0, stream>>>(feature, xyz, nxyz, nfeat, knn, invstd,
                                               alpha, beta, w_tr, b_tr, w1, b1, w2, b2,
                                               bn_tr, bn_1, bnpart, out1);
    bn_finalize<<<64, 256, 0, stream>>>(bnpart, g_tr, be_tr, bn_tr);
    mlp_kernel<1><<<B_ * S_, 256, 0, stream>>>(feature, xyz, nxyz, nfeat, knn, invstd,
                                               alpha, beta, w_tr, b_tr, w1, b1, w2, b2,
                                               bn_tr, bn_1, bnpart, out1);
    bn_finalize<<<64, 256, 0, stream>>>(bnpart, g1, be1, bn_1);
    mlp_kernel<2><<<B_ * S_, 256, 0, stream>>>(feature, xyz, nxyz, nfeat, knn, invstd,
                                               alpha, beta, w_tr, b_tr, w1, b1, w2, b2,
                                               bn_tr, bn_1, bnpart, out1);
  }
}

// Round 6
// 1537.658 us; speedup vs baseline: 1.3605x; 1.3605x over previous
//
#include <hip/hip_runtime.h>
#include <cfloat>
#include <math.h>

#define B_ 8
#define N_ 4096
#define D_ 64
#define S_ 1024
#define K_ 32
#define CIN_ 131  // 2*D + 3

typedef float f32x2 __attribute__((ext_vector_type(2)));

// Move a u64 across lanes with a constant DPP control (2x 32-bit update_dpp).
template <int CTRL>
__device__ __forceinline__ unsigned long long dpp_u64(unsigned long long k) {
  int lo = (int)(unsigned int)k, hi = (int)(unsigned int)(k >> 32);
  lo = __builtin_amdgcn_update_dpp(lo, lo, CTRL, 0xf, 0xf, false);
  hi = __builtin_amdgcn_update_dpp(hi, hi, CTRL, 0xf, 0xf, false);
  return ((unsigned long long)(unsigned int)hi << 32) | (unsigned int)lo;
}

// Wave(64)-wide float max via DPP (VALU pipe). Result broadcast via readlane 63.
__device__ __forceinline__ float wave_max_f32_dpp(float v) {
  int x = __float_as_int(v);
#define STEP(ctrl)                                                        \
  {                                                                       \
    int t = __builtin_amdgcn_update_dpp(x, x, ctrl, 0xf, 0xf, false);     \
    v = fmaxf(v, __int_as_float(t));                                      \
    x = __float_as_int(v);                                                \
  }
  STEP(0x111)
  STEP(0x112)
  STEP(0x114)
  STEP(0x118)
  STEP(0x142)
  STEP(0x143)
#undef STEP
  return __int_as_float(__builtin_amdgcn_readlane(x, 63));
}

// ---------------------------------------------------------------------------
// FPS (r2-validated, 589us): blocks 0..7, 256 thr, thread t owns [16t,16t+16).
// Packed f32x2 dist update (bit-exact IEEE, contract(off)), fmax tree local
// max, descending equality scan argmax, DPP wave max + ballot, 1 barrier,
// keyp LDS + 2-DPP u64 merge. NOTE r4 lesson: 1-wave/64pt variant spills
// (256 f32 live state > VALU-addressable VGPR file) — do not retry.
// Blocks 8..519 transpose feature [b][c][n] -> featT [b][n][c].
// ---------------------------------------------------------------------------
__global__ __launch_bounds__(256) void fps_kernel(const float* __restrict__ xyz,
                                                  int* __restrict__ fps_idx,
                                                  float* __restrict__ nxyz,
                                                  float* __restrict__ out0,
                                                  const float* __restrict__ feature,
                                                  float* __restrict__ featT) {
#pragma clang fp contract(off)
  const int tid = threadIdx.x;
  __shared__ __align__(16) float4 sp[N_];    // 64 KB coord mirror / transpose tile
  __shared__ int si[S_];
  __shared__ unsigned long long keyp[2][4];
  if (blockIdx.x >= 8) {
    // ---- fused transpose (validated r7 transpose_feat logic, 256 thr) ----
    const int blk = blockIdx.x - 8;
    const int b = blk >> 6, n0 = (blk & 63) * 64;
    float* tile = (float*)sp;  // 64*65 floats = 16.6 KB
#pragma unroll
    for (int i = 0; i < 16; i++) {
      int c = i * 4 + (tid >> 6), nl = tid & 63;
      tile[c * 65 + nl] = feature[((size_t)b * 64 + c) * N_ + n0 + nl];
    }
    __syncthreads();
#pragma unroll
    for (int i = 0; i < 16; i++) {
      int nl = i * 4 + (tid >> 6), c = tid & 63;
      featT[((size_t)b * N_ + n0 + nl) * 64 + c] = tile[c * 65 + nl];
    }
    return;
  }
  const int b = blockIdx.x;
  const float* xb = xyz + (size_t)b * 3 * N_;
  const float4* xv = (const float4*)xb;
  f32x2 pxv[8], pyv[8], pzv[8];
  float dist[16];
#pragma unroll
  for (int q = 0; q < 4; q++) {
    float4 X = xv[4 * tid + q];
    float4 Y = xv[1024 + 4 * tid + q];
    float4 Z = xv[2048 + 4 * tid + q];
    pxv[2 * q] = (f32x2){X.x, X.y};  pxv[2 * q + 1] = (f32x2){X.z, X.w};
    pyv[2 * q] = (f32x2){Y.x, Y.y};  pyv[2 * q + 1] = (f32x2){Y.z, Y.w};
    pzv[2 * q] = (f32x2){Z.x, Z.y};  pzv[2 * q + 1] = (f32x2){Z.z, Z.w};
  }
#pragma unroll
  for (int j = 0; j < 8; j++) {
    dist[2 * j] = 1e10f;
    dist[2 * j + 1] = 1e10f;
    sp[16 * tid + 2 * j] = make_float4(pxv[j].x, pyv[j].x, pzv[j].x, 0.f);
    sp[16 * tid + 2 * j + 1] = make_float4(pxv[j].y, pyv[j].y, pzv[j].y, 0.f);
  }
  if (tid == 0) si[0] = 0;
  __syncthreads();
  float cx = sp[0].x, cy = sp[0].y, cz = sp[0].z;
  const int wav = tid >> 6, lane = tid & 63;
  for (int s = 1; s < S_; s++) {
    // --- packed dist update (exact: pk lanes are independent IEEE ops,
    //     same op order (dx*dx + dy*dy) + dz*dz as validated rounds) ---
    const f32x2 c2x = {cx, cx}, c2y = {cy, cy}, c2z = {cz, cz};
#pragma unroll
    for (int j = 0; j < 8; j++) {
      f32x2 dx = pxv[j] - c2x;
      f32x2 dy = pyv[j] - c2y;
      f32x2 dz = pzv[j] - c2z;
      f32x2 d = (dx * dx + dy * dy) + dz * dz;
      dist[2 * j] = fminf(dist[2 * j], d.x);
      dist[2 * j + 1] = fminf(dist[2 * j + 1], d.y);
    }
    // --- local max via fmax tree (order-independent, exact) ---
    float t8[8], t4[4];
#pragma unroll
    for (int j = 0; j < 8; j++) t8[j] = fmaxf(dist[2 * j], dist[2 * j + 1]);
#pragma unroll
    for (int j = 0; j < 4; j++) t4[j] = fmaxf(t8[2 * j], t8[2 * j + 1]);
    float best = fmaxf(fmaxf(t4[0], t4[1]), fmaxf(t4[2], t4[3]));
    // --- local argmax: descending equality scan -> first (smallest) index
    //     with dist == best; identical tie-break to strict-> ascending scan ---
    int bi = 16 * tid;
#pragma unroll
    for (int i = 15; i >= 0; i--)
      if (dist[i] == best) bi = 16 * tid + i;
    float wmax = wave_max_f32_dpp(best);
    unsigned long long m = __ballot(best == wmax);
    int l = __ffsll(m) - 1;
    int widx = __builtin_amdgcn_readlane(bi, l);
    if (lane == 0)
      keyp[s & 1][wav] =
          ((unsigned long long)(unsigned int)__float_as_int(wmax) << 32) |
          (unsigned int)(4095 - widx);
    __syncthreads();
    // merge 4 per-wave winners: 1 LDS read + 2 DPP steps (period-4 in quads)
    unsigned long long k = keyp[s & 1][lane & 3];
    unsigned long long t;
    t = dpp_u64<0xB1>(k); if (t > k) k = t;  // quad_perm xor 1
    t = dpp_u64<0x4E>(k); if (t > k) k = t;  // quad_perm xor 2
    int bix = 4095 - (int)(k & 0xfffull);
    if (tid == 0) si[s] = bix;
    float4 c = sp[bix];
    cx = c.x; cy = c.y; cz = c.z;
  }
  __syncthreads();
  for (int e = tid; e < S_; e += 256) {
    int n = si[e];
    fps_idx[b * S_ + e] = n;
    float4 c = sp[n];
    nxyz[(size_t)(b * S_ + e) * 3 + 0] = c.x;
    nxyz[(size_t)(b * S_ + e) * 3 + 1] = c.y;
    nxyz[(size_t)(b * S_ + e) * 3 + 2] = c.z;
    out0[(size_t)b * 3 * S_ + e] = c.x;
    out0[(size_t)b * 3 * S_ + S_ + e] = c.y;
    out0[(size_t)b * 3 * S_ + 2 * S_ + e] = c.z;
  }
}

// ---------------------------------------------------------------------------
// kNN (validated r2). Packed f32x2 distance init, selection logic unchanged.
// Blocks >= 8192 perform the fused anchor-feature gather from featT.
// ---------------------------------------------------------------------------
__global__ __launch_bounds__(256) void knn_kernel(const float* __restrict__ xyz,
                                                  const float* __restrict__ nxyz,
                                                  int* __restrict__ knn,
                                                  const float* __restrict__ featT,
                                                  const int* __restrict__ fps_i,
                                                  float* __restrict__ nfeat) {
#pragma clang fp contract(off)
  const int bs = blockIdx.x, tid = threadIdx.x;
  if (bs >= 8192) {
    int e = (bs - 8192) * 256 + tid;  // < B*S*D
    int bsx = e >> 6, c = e & 63;
    int bq = bsx >> 10;
    int n = fps_i[bsx];
    nfeat[e] = featT[((size_t)bq * N_ + n) * 64 + c];
    return;
  }
  const int b = bs >> 10;
  const float* xb = xyz + (size_t)b * 3 * N_;
  const float cx = nxyz[(size_t)bs * 3], cy = nxyz[(size_t)bs * 3 + 1], cz = nxyz[(size_t)bs * 3 + 2];
  const float cn = (cx * cx + cy * cy) + cz * cz;
  const f32x2 c2x = {cx, cx}, c2y = {cy, cy}, c2z = {cz, cz};
  const f32x2 c2n = {cn, cn}, two = {2.0f, 2.0f};
  float d[16];
#pragma unroll
  for (int j = 0; j < 8; j++) {
    int n0 = (2 * j) * 256 + tid, n1 = n0 + 256;
    f32x2 px = {xb[n0], xb[n1]};
    f32x2 py = {xb[N_ + n0], xb[N_ + n1]};
    f32x2 pz = {xb[2 * N_ + n0], xb[2 * N_ + n1]};
    f32x2 pn = (px * px + py * py) + pz * pz;
    f32x2 dot = (c2x * px + c2y * py) + c2z * pz;
    f32x2 dd = (c2n + pn) - two * dot;
    d[2 * j] = dd.x;
    d[2 * j + 1] = dd.y;
  }
  float mv = FLT_MAX;
  int mi = tid;
#pragma unroll
  for (int i = 0; i < 16; i++)
    if (d[i] < mv) { mv = d[i]; mi = i * 256 + tid; }
  __shared__ unsigned long long keyp[2][4];
  __shared__ int skk[K_];
  const int wav = tid >> 6, lane = tid & 63;
  for (int j = 0; j < K_; j++) {
    unsigned int u = __float_as_uint(mv);
    u ^= ((unsigned int)((int)u >> 31) | 0x80000000u);
    unsigned long long key = ((unsigned long long)u << 32) | (unsigned int)mi;
#pragma unroll
    for (int off = 32; off >= 1; off >>= 1) {
      unsigned long long ok = __shfl_xor(key, off);
      if (ok < key) key = ok;
    }
    if (lane == 0) keyp[j & 1][wav] = key;
    __syncthreads();
    unsigned long long kmin = keyp[j & 1][0];
#pragma unroll
    for (int w = 1; w < 4; w++) {
      unsigned long long k2 = keyp[j & 1][w];
      if (k2 < kmin) kmin = k2;
    }
    int g = (int)(kmin & 0xffffffffull);
    if (tid == 0) skk[j] = g;
    if ((g & 255) == tid) {
      int sl = g >> 8;
#pragma unroll
      for (int i = 0; i < 16; i++)
        if (i == sl) d[i] = FLT_MAX;
      mv = FLT_MAX; mi = tid;
#pragma unroll
      for (int i = 0; i < 16; i++)
        if (d[i] < mv) { mv = d[i]; mi = i * 256 + tid; }
    }
  }
  __syncthreads();
  if (tid < K_) knn[(size_t)bs * K_ + tid] = skk[tid];
}

// ===========================================================================
// ============ FALLBACK (r6) kernels — used when ws is small ================
// ===========================================================================
__global__ __launch_bounds__(256) void gather_nf(const float* __restrict__ feature,
                                                 const int* __restrict__ fps_i,
                                                 float* __restrict__ nfeat) {
  int e = blockIdx.x * 256 + threadIdx.x;
  int b = e >> 16, rem = e & 65535;
  int s = rem >> 6, c = rem & 63;
  int n = fps_i[b * S_ + s];
  nfeat[e] = feature[((size_t)b * 64 + c) * N_ + n];
}

__global__ __launch_bounds__(256) void std_partial(const float* __restrict__ feature,
                                                   const float* __restrict__ xyz,
                                                   const float* __restrict__ nxyz,
                                                   const float* __restrict__ nfeat,
                                                   const int* __restrict__ knn,
                                                   float* __restrict__ outp) {
  const int blk = blockIdx.x, tid = threadIdx.x;
  const int b = blk >> 6, chunk = blk & 63;
  float s = 0.f, q = 0.f;
  for (int e = tid; e < 16 * K_ * 67; e += 256) {
    int so = e / (K_ * 67);
    int rem = e - so * (K_ * 67);
    int kk = rem / 67;
    int c = rem - kk * 67;
    int bs = b * S_ + chunk * 16 + so;
    int n = knn[(size_t)bs * K_ + kk];
    float raw = (c < 64) ? feature[((size_t)b * 64 + c) * N_ + n]
                         : xyz[((size_t)b * 3 + (c - 64)) * N_ + n];
    float anc = (c < 64) ? nfeat[(size_t)bs * 64 + c]
                         : nxyz[(size_t)bs * 3 + (c - 64)];
    float dd = raw - anc;
    s += dd; q += dd * dd;
  }
#pragma unroll
  for (int off = 32; off >= 1; off >>= 1) { s += __shfl_xor(s, off); q += __shfl_xor(q, off); }
  __shared__ float rs[4], rq[4];
  if ((tid & 63) == 0) { rs[tid >> 6] = s; rq[tid >> 6] = q; }
  __syncthreads();
  if (tid == 0) {
    outp[blk * 2] = rs[0] + rs[1] + rs[2] + rs[3];
    outp[blk * 2 + 1] = rq[0] + rq[1] + rq[2] + rq[3];
  }
}

__global__ void std_final(const float* __restrict__ part, float* __restrict__ invstd) {
  int b = threadIdx.x;
  if (b < B_) {
    double s = 0.0, q = 0.0;
    for (int i = 0; i < 64; i++) {
      s += (double)part[(b * 64 + i) * 2];
      q += (double)part[(b * 64 + i) * 2 + 1];
    }
    const double n = (double)(S_ * K_ * 67);
    double var = (q - s * s / n) / (n - 1.0);
    invstd[b] = (float)(1.0 / (sqrt(var) + 1e-5));
  }
}

template <int MODE>
__global__ __launch_bounds__(256, 2) void mlp_kernel(
    const float* __restrict__ feature, const float* __restrict__ xyz,
    const float* __restrict__ nxyz, const float* __restrict__ nfeat,
    const int* __restrict__ knn, const float* __restrict__ invstd,
    const float* __restrict__ alpha, const float* __restrict__ beta,
    const float* __restrict__ w_tr, const float* __restrict__ b_tr,
    const float* __restrict__ w1, const float* __restrict__ b1,
    const float* __restrict__ w2, const float* __restrict__ b2,
    const float* __restrict__ bn_tr, const float* __restrict__ bn_1,
    float* __restrict__ bnpart, float* __restrict__ out1) {
  __shared__ __align__(16) float pool[15556];
  float* Wt = pool;
  float* xin = pool + 8516;
  float* ub = xin;
  float* tb = pool + 8516 + 4192;
  float* part = pool + 8516 + 4192 + 2304;
  int* sknn = (int*)(part + 512);
  const int bs = blockIdx.x, tid = threadIdx.x;
  const int b = bs >> 10, s = bs & 1023;
  if (tid < K_) sknn[tid] = knn[(size_t)bs * K_ + tid];
  for (int e = tid; e < 64 * 131; e += 256) {
    int o = e / 131, c = e - o * 131;
    Wt[c * 65 + o] = w_tr[e];
  }
  __syncthreads();
  const float inv = invstd[b];
  for (int e = tid; e < CIN_ * K_; e += 256) {
    int c = e >> 5, kk = e & 31;
    float v;
    if (c < 67) {
      int n = sknn[kk];
      float raw = (c < 64) ? feature[((size_t)b * 64 + c) * N_ + n]
                           : xyz[((size_t)b * 3 + (c - 64)) * N_ + n];
      float anc = (c < 64) ? nfeat[(size_t)bs * 64 + c]
                           : nxyz[(size_t)bs * 3 + (c - 64)];
      v = alpha[c] * ((raw - anc) * inv) + beta[c];
    } else {
      v = nfeat[(size_t)bs * 64 + (c - 67)];
    }
    xin[e] = v;
  }
  __syncthreads();
  const int o = tid & 63, kkb = (tid >> 6) * 8;
  float acc[8];
  {
    float bv = b_tr[o];
#pragma unroll
    for (int j = 0; j < 8; j++) acc[j] = bv;
  }
  for (int c = 0; c < CIN_; c++) {
    float w = Wt[c * 65 + o];
    const float4 xa = *(const float4*)(xin + c * 32 + kkb);
    const float4 xb4 = *(const float4*)(xin + c * 32 + kkb + 4);
    acc[0] += w * xa.x; acc[1] += w * xa.y; acc[2] += w * xa.z; acc[3] += w * xa.w;
    acc[4] += w * xb4.x; acc[5] += w * xb4.y; acc[6] += w * xb4.z; acc[7] += w * xb4.w;
  }
  if (MODE == 0) {
    float s8 = 0.f, q8 = 0.f;
#pragma unroll
    for (int j = 0; j < 8; j++) { s8 += acc[j]; q8 += acc[j] * acc[j]; }
    part[(tid >> 6) * 64 + o] = s8;
    part[256 + (tid >> 6) * 64 + o] = q8;
    __syncthreads();
    if (tid < 64) {
      float ss = 0.f, qq = 0.f;
      for (int g = 0; g < 4; g++) { ss += part[g * 64 + tid]; qq += part[256 + g * 64 + tid]; }
      bnpart[(size_t)bs * 128 + tid] = ss;
      bnpart[(size_t)bs * 128 + 64 + tid] = qq;
    }
    return;
  }
  float tv[8];
  {
    float sc = bn_tr[o], sh = bn_tr[64 + o];
#pragma unroll
    for (int j = 0; j < 8; j++) {
      tv[j] = fmaxf(fmaf(sc, acc[j], sh), 0.f);
      tb[o * 36 + kkb + j] = tv[j];
    }
  }
  __syncthreads();
  for (int e = tid; e < 64 * 64; e += 256) {
    int oo = e >> 6, c = e & 63;
    Wt[c * 65 + oo] = w1[e];
  }
  __syncthreads();
  float acc2[8];
  {
    float bv = b1[o];
#pragma unroll
    for (int j = 0; j < 8; j++) acc2[j] = bv;
  }
  for (int c = 0; c < 64; c++) {
    float w = Wt[c * 65 + o];
    const float4 ta = *(const float4*)(tb + c * 36 + kkb);
    const float4 ta2 = *(const float4*)(tb + c * 36 + kkb + 4);
    acc2[0] += w * ta.x; acc2[1] += w * ta.y; acc2[2] += w * ta.z; acc2[3] += w * ta.w;
    acc2[4] += w * ta2.x; acc2[5] += w * ta2.y; acc2[6] += w * ta2.z; acc2[7] += w * ta2.w;
  }
  if (MODE == 1) {
    float s8 = 0.f, q8 = 0.f;
#pragma unroll
    for (int j = 0; j < 8; j++) { s8 += acc2[j]; q8 += acc2[j] * acc2[j]; }
    part[(tid >> 6) * 64 + o] = s8;
    part[256 + (tid >> 6) * 64 + o] = q8;
    __syncthreads();
    if (tid < 64) {
      float ss = 0.f, qq = 0.f;
      for (int g = 0; g < 4; g++) { ss += part[g * 64 + tid]; qq += part[256 + g * 64 + tid]; }
      bnpart[(size_t)bs * 128 + tid] = ss;
      bnpart[(size_t)bs * 128 + 64 + tid] = qq;
    }
    return;
  }
  {
    float sc = bn_1[o], sh = bn_1[64 + o];
#pragma unroll
    for (int j = 0; j < 8; j++) ub[o * 36 + kkb + j] = fmaxf(fmaf(sc, acc2[j], sh), 0.f);
  }
  __syncthreads();
  for (int e = tid; e < 64 * 64; e += 256) {
    int oo = e >> 6, c = e & 63;
    Wt[c * 65 + oo] = w2[e];
  }
  __syncthreads();
  float acc3[8];
  {
    float bv = b2[o];
#pragma unroll
    for (int j = 0; j < 8; j++) acc3[j] = bv;
  }
  for (int c = 0; c < 64; c++) {
    float w = Wt[c * 65 + o];
    const float4 ua = *(const float4*)(ub + c * 36 + kkb);
    const float4 ua2 = *(const float4*)(ub + c * 36 + kkb + 4);
    acc3[0] += w * ua.x; acc3[1] += w * ua.y; acc3[2] += w * ua.z; acc3[3] += w * ua.w;
    acc3[4] += w * ua2.x; acc3[5] += w * ua2.y; acc3[6] += w * ua2.z; acc3[7] += w * ua2.w;
  }
  float m = 0.f;
#pragma unroll
  for (int j = 0; j < 8; j++) m = fmaxf(m, fmaxf(acc3[j] + tv[j], 0.f));
  part[(tid >> 6) * 64 + o] = m;
  __syncthreads();
  if (tid < 64) {
    float mm = part[tid];
    for (int g = 1; g < 4; g++) mm = fmaxf(mm, part[g * 64 + tid]);
    out1[((size_t)b * 64 + tid) * S_ + s] = mm;
  }
}

// ---------------------------------------------------------------------------
// BN finalize (shared by both paths).
// ---------------------------------------------------------------------------
__global__ __launch_bounds__(256) void bn_finalize(const float* __restrict__ part,
                                                   const float* __restrict__ g,
                                                   const float* __restrict__ be,
                                                   float* __restrict__ bnout) {
  const int ch = blockIdx.x, tid = threadIdx.x;
  double s = 0.0, q = 0.0;
  for (int i = tid; i < B_ * S_; i += 256) {
    s += (double)part[(size_t)i * 128 + ch];
    q += (double)part[(size_t)i * 128 + 64 + ch];
  }
#pragma unroll
  for (int off = 32; off >= 1; off >>= 1) { s += __shfl_xor(s, off); q += __shfl_xor(q, off); }
  __shared__ double ls[4], lq[4];
  if ((tid & 63) == 0) { ls[tid >> 6] = s; lq[tid >> 6] = q; }
  __syncthreads();
  if (tid == 0) {
    double Ssum = ls[0] + ls[1] + ls[2] + ls[3];
    double Qsum = lq[0] + lq[1] + lq[2] + lq[3];
    const double n = (double)(B_ * S_ * K_);
    double mu = Ssum / n;
    double var = Qsum / n - mu * mu;
    double sc = (double)g[ch] / sqrt(var + 1e-5);
    bnout[ch] = (float)sc;
    bnout[64 + ch] = (float)((double)be[ch] - mu * sc);
  }
}

// ===========================================================================
// ================== CACHE-PATH kernels (large workspace) ===================
// ===========================================================================

// Fused diff computation + std partials. 1024 blocks x 8 groups.
__global__ __launch_bounds__(256) void prep_kernel(const float* __restrict__ featT,
                                                   const float* __restrict__ xyz,
                                                   const float* __restrict__ nxyz,
                                                   const float* __restrict__ nfeat,
                                                   const int* __restrict__ knn,
                                                   float* __restrict__ dcache,
                                                   float* __restrict__ outp) {
  const int blk = blockIdx.x, tid = threadIdx.x;
  __shared__ int sk[32];
  float s = 0.f, q = 0.f;
  const int c = tid & 63, qd = tid >> 6;
  for (int g = 0; g < 8; g++) {
    const int bs = blk * 8 + g, b = bs >> 10;
    if (tid < 32) sk[tid] = knn[(size_t)bs * K_ + tid];
    __syncthreads();
    float anc = nfeat[(size_t)bs * 64 + c];
#pragma unroll
    for (int it = 0; it < 8; it++) {
      int kk = it * 4 + qd;
      int n = sk[kk];
      float dd = featT[((size_t)b * N_ + n) * 64 + c] - anc;
      s += dd; q += dd * dd;
      dcache[((size_t)bs * 32 + kk) * 68 + c] = dd;
    }
    if (tid < 96) {
      int c3 = tid >> 5, kk = tid & 31;
      int n = sk[kk];
      float dd = xyz[((size_t)b * 3 + c3) * N_ + n] - nxyz[(size_t)bs * 3 + c3];
      s += dd; q += dd * dd;
      dcache[((size_t)bs * 32 + kk) * 68 + 64 + c3] = dd;
    }
    __syncthreads();
  }
#pragma unroll
  for (int off = 32; off >= 1; off >>= 1) { s += __shfl_xor(s, off); q += __shfl_xor(q, off); }
  __shared__ float rs[4], rq[4];
  if ((tid & 63) == 0) { rs[tid >> 6] = s; rq[tid >> 6] = q; }
  __syncthreads();
  if (tid == 0) {
    outp[blk * 2] = rs[0] + rs[1] + rs[2] + rs[3];
    outp[blk * 2 + 1] = rq[0] + rq[1] + rq[2] + rq[3];
  }
}

__global__ void std_final_c(const float* __restrict__ part, float* __restrict__ invstd) {
  int b = threadIdx.x;
  if (b < B_) {
    double s = 0.0, q = 0.0;
    for (int i = 0; i < 128; i++) {
      s += (double)part[(b * 128 + i) * 2];
      q += (double)part[(b * 128 + i) * 2 + 1];
    }
    const double n = (double)(S_ * K_ * 67);
    double var = (q - s * s / n) / (n - 1.0);
    invstd[b] = (float)(1.0 / (sqrt(var) + 1e-5));
  }
}

// MLP stage 0: xin from dcache (coalesced), conv_tr, stats + tcache store.
// r5 A/B: 2-o x 4-k register tile -> per c: 1 ds_read_b64 (w pair, stride 66
// for 8B alignment) + 1 ds_read_b128 (x quad) feeds 8 FMA (was 3 LDS / 8 FMA).
// Per-output accumulation order over c unchanged -> conv bit-exact.
__global__ __launch_bounds__(256, 2) void mlp0c(
    const float* __restrict__ dcache, const float* __restrict__ nfeat,
    const float* __restrict__ invstd,
    const float* __restrict__ alpha, const float* __restrict__ beta,
    const float* __restrict__ w_tr, const float* __restrict__ b_tr,
    float* __restrict__ bnpart, float* __restrict__ tcache) {
  __shared__ __align__(16) float pool[8646 + 4192 + 1024];
  float* Wt = pool;                  // 131 x 66
  float* xin = pool + 8646;          // 131 x 32
  float* part = pool + 8646 + 4192;  // 1024
  const int bs = blockIdx.x, tid = threadIdx.x;
  const int b = bs >> 10;
  for (int e = tid; e < 64 * 131; e += 256) {
    int o = e / 131, c = e - o * 131;
    Wt[c * 66 + o] = w_tr[e];
  }
  const float inv = invstd[b];
  {
    const int c = tid & 63, qd = tid >> 6;
    float al = alpha[c], bev = beta[c];
#pragma unroll
    for (int it = 0; it < 8; it++) {
      int kk = it * 4 + qd;
      xin[c * 32 + kk] = al * (dcache[((size_t)bs * 32 + kk) * 68 + c] * inv) + bev;
    }
    if (tid < 96) {
      int c3 = 64 + (tid >> 5), kk = tid & 31;
      xin[c3 * 32 + kk] =
          alpha[c3] * (dcache[((size_t)bs * 32 + kk) * 68 + c3] * inv) + beta[c3];
    }
    for (int e = tid; e < 2048; e += 256) {
      int cc = 67 + (e >> 5), kk = e & 31;
      xin[cc * 32 + kk] = nfeat[(size_t)bs * 64 + (e >> 5)];
    }
  }
  __syncthreads();
  const int o0 = (tid >> 3) * 2, k0 = (tid & 7) * 4, kq = tid & 7;
  float acc0[4], acc1[4];
  {
    float bv0 = b_tr[o0], bv1 = b_tr[o0 + 1];
#pragma unroll
    for (int j = 0; j < 4; j++) { acc0[j] = bv0; acc1[j] = bv1; }
  }
  for (int c = 0; c < CIN_; c++) {
    const f32x2 w = *(const f32x2*)(Wt + c * 66 + o0);
    const float4 xa = *(const float4*)(xin + c * 32 + k0);
    acc0[0] += w.x * xa.x; acc0[1] += w.x * xa.y; acc0[2] += w.x * xa.z; acc0[3] += w.x * xa.w;
    acc1[0] += w.y * xa.x; acc1[1] += w.y * xa.y; acc1[2] += w.y * xa.z; acc1[3] += w.y * xa.w;
  }
  {
    float4* tp0 = (float4*)(tcache + ((size_t)bs * 64 + o0) * 32 + k0);
    *tp0 = make_float4(acc0[0], acc0[1], acc0[2], acc0[3]);
    float4* tp1 = (float4*)(tcache + ((size_t)bs * 64 + o0 + 1) * 32 + k0);
    *tp1 = make_float4(acc1[0], acc1[1], acc1[2], acc1[3]);
  }
  float s0 = 0.f, q0 = 0.f, s1 = 0.f, q1 = 0.f;
#pragma unroll
  for (int j = 0; j < 4; j++) {
    s0 += acc0[j]; q0 += acc0[j] * acc0[j];
    s1 += acc1[j]; q1 += acc1[j] * acc1[j];
  }
  part[kq * 64 + o0] = s0;
  part[kq * 64 + o0 + 1] = s1;
  part[512 + kq * 64 + o0] = q0;
  part[512 + kq * 64 + o0 + 1] = q1;
  __syncthreads();
  if (tid < 64) {
    float ss = 0.f, qq = 0.f;
    for (int g = 0; g < 8; g++) { ss += part[g * 64 + tid]; qq += part[512 + g * 64 + tid]; }
    bnpart[(size_t)bs * 128 + tid] = ss;
    bnpart[(size_t)bs * 128 + 64 + tid] = qq;
  }
}

// MLP stage 1: t = bn+relu(tcache); conv1; stats + ucache store. (r5 A/B tile)
__global__ __launch_bounds__(256, 3) void mlp1c(
    const float* __restrict__ tcache, const float* __restrict__ bn_tr,
    const float* __restrict__ w1, const float* __restrict__ b1,
    float* __restrict__ bnpart, float* __restrict__ ucache) {
  __shared__ __align__(16) float pool[4224 + 2304 + 1024];
  float* Wt = pool;                  // 64 x 66
  float* tb = pool + 4224;           // 64 x 36
  float* part = pool + 4224 + 2304;  // 1024
  const int bs = blockIdx.x, tid = threadIdx.x;
  const int o0 = (tid >> 3) * 2, k0 = (tid & 7) * 4, kq = tid & 7;
  for (int e = tid; e < 64 * 64; e += 256) {
    int oo = e >> 6, c = e & 63;
    Wt[c * 66 + oo] = w1[e];
  }
  {
    const float4 t0 = *(const float4*)(tcache + ((size_t)bs * 64 + o0) * 32 + k0);
    const float4 t1 = *(const float4*)(tcache + ((size_t)bs * 64 + o0 + 1) * 32 + k0);
    float sc0 = bn_tr[o0], sh0 = bn_tr[64 + o0];
    float sc1 = bn_tr[o0 + 1], sh1 = bn_tr[64 + o0 + 1];
    *(float4*)(tb + o0 * 36 + k0) =
        make_float4(fmaxf(fmaf(sc0, t0.x, sh0), 0.f), fmaxf(fmaf(sc0, t0.y, sh0), 0.f),
                    fmaxf(fmaf(sc0, t0.z, sh0), 0.f), fmaxf(fmaf(sc0, t0.w, sh0), 0.f));
    *(float4*)(tb + (o0 + 1) * 36 + k0) =
        make_float4(fmaxf(fmaf(sc1, t1.x, sh1), 0.f), fmaxf(fmaf(sc1, t1.y, sh1), 0.f),
                    fmaxf(fmaf(sc1, t1.z, sh1), 0.f), fmaxf(fmaf(sc1, t1.w, sh1), 0.f));
  }
  __syncthreads();
  float acc0[4], acc1[4];
  {
    float bv0 = b1[o0], bv1 = b1[o0 + 1];
#pragma unroll
    for (int j = 0; j < 4; j++) { acc0[j] = bv0; acc1[j] = bv1; }
  }
  for (int c = 0; c < 64; c++) {
    const f32x2 w = *(const f32x2*)(Wt + c * 66 + o0);
    const float4 ta = *(const float4*)(tb + c * 36 + k0);
    acc0[0] += w.x * ta.x; acc0[1] += w.x * ta.y; acc0[2] += w.x * ta.z; acc0[3] += w.x * ta.w;
    acc1[0] += w.y * ta.x; acc1[1] += w.y * ta.y; acc1[2] += w.y * ta.z; acc1[3] += w.y * ta.w;
  }
  {
    float4* up0 = (float4*)(ucache + ((size_t)bs * 64 + o0) * 32 + k0);
    *up0 = make_float4(acc0[0], acc0[1], acc0[2], acc0[3]);
    float4* up1 = (float4*)(ucache + ((size_t)bs * 64 + o0 + 1) * 32 + k0);
    *up1 = make_float4(acc1[0], acc1[1], acc1[2], acc1[3]);
  }
  float s0 = 0.f, q0 = 0.f, s1 = 0.f, q1 = 0.f;
#pragma unroll
  for (int j = 0; j < 4; j++) {
    s0 += acc0[j]; q0 += acc0[j] * acc0[j];
    s1 += acc1[j]; q1 += acc1[j] * acc1[j];
  }
  part[kq * 64 + o0] = s0;
  part[kq * 64 + o0 + 1] = s1;
  part[512 + kq * 64 + o0] = q0;
  part[512 + kq * 64 + o0 + 1] = q1;
  __syncthreads();
  if (tid < 64) {
    float ss = 0.f, qq = 0.f;
    for (int g = 0; g < 8; g++) { ss += part[g * 64 + tid]; qq += part[512 + g * 64 + tid]; }
    bnpart[(size_t)bs * 128 + tid] = ss;
    bnpart[(size_t)bs * 128 + 64 + tid] = qq;
  }
}

// MLP stage 2: u = bn+relu(ucache); conv2; residual with bn+relu(tcache); max.
// (r5 A/B tile; max over k is order-independent -> exact)
__global__ __launch_bounds__(256, 3) void mlp2c(
    const float* __restrict__ tcache, const float* __restrict__ ucache,
    const float* __restrict__ bn_tr, const float* __restrict__ bn_1,
    const float* __restrict__ w2, const float* __restrict__ b2,
    float* __restrict__ out1) {
  __shared__ __align__(16) float pool[4224 + 2304 + 512];
  float* Wt = pool;                  // 64 x 66
  float* ub = pool + 4224;           // 64 x 36
  float* part = pool + 4224 + 2304;  // 512
  const int bs = blockIdx.x, tid = threadIdx.x;
  const int b = bs >> 10, s = bs & 1023;
  const int o0 = (tid >> 3) * 2, k0 = (tid & 7) * 4, kq = tid & 7;
  for (int e = tid; e < 64 * 64; e += 256) {
    int oo = e >> 6, c = e & 63;
    Wt[c * 66 + oo] = w2[e];
  }
  {
    const float4 u0 = *(const float4*)(ucache + ((size_t)bs * 64 + o0) * 32 + k0);
    const float4 u1 = *(const float4*)(ucache + ((size_t)bs * 64 + o0 + 1) * 32 + k0);
    float sc0 = bn_1[o0], sh0 = bn_1[64 + o0];
    float sc1 = bn_1[o0 + 1], sh1 = bn_1[64 + o0 + 1];
    *(float4*)(ub + o0 * 36 + k0) =
        make_float4(fmaxf(fmaf(sc0, u0.x, sh0), 0.f), fmaxf(fmaf(sc0, u0.y, sh0), 0.f),
                    fmaxf(fmaf(sc0, u0.z, sh0), 0.f), fmaxf(fmaf(sc0, u0.w, sh0), 0.f));
    *(float4*)(ub + (o0 + 1) * 36 + k0) =
        make_float4(fmaxf(fmaf(sc1, u1.x, sh1), 0.f), fmaxf(fmaf(sc1, u1.y, sh1), 0.f),
                    fmaxf(fmaf(sc1, u1.z, sh1), 0.f), fmaxf(fmaf(sc1, u1.w, sh1), 0.f));
  }
  __syncthreads();
  float acc0[4], acc1[4];
  {
    float bv0 = b2[o0], bv1 = b2[o0 + 1];
#pragma unroll
    for (int j = 0; j < 4; j++) { acc0[j] = bv0; acc1[j] = bv1; }
  }
  for (int c = 0; c < 64; c++) {
    const f32x2 w = *(const f32x2*)(Wt + c * 66 + o0);
    const float4 ua = *(const float4*)(ub + c * 36 + k0);
    acc0[0] += w.x * ua.x; acc0[1] += w.x * ua.y; acc0[2] += w.x * ua.z; acc0[3] += w.x * ua.w;
    acc1[0] += w.y * ua.x; acc1[1] += w.y * ua.y; acc1[2] += w.y * ua.z; acc1[3] += w.y * ua.w;
  }
  float m0 = 0.f, m1 = 0.f;
  {
    const float4 t0 = *(const float4*)(tcache + ((size_t)bs * 64 + o0) * 32 + k0);
    const float4 t1 = *(const float4*)(tcache + ((size_t)bs * 64 + o0 + 1) * 32 + k0);
    float sc0 = bn_tr[o0], sh0 = bn_tr[64 + o0];
    float sc1 = bn_tr[o0 + 1], sh1 = bn_tr[64 + o0 + 1];
    float tv0[4] = {fmaxf(fmaf(sc0, t0.x, sh0), 0.f), fmaxf(fmaf(sc0, t0.y, sh0), 0.f),
                    fmaxf(fmaf(sc0, t0.z, sh0), 0.f), fmaxf(fmaf(sc0, t0.w, sh0), 0.f)};
    float tv1[4] = {fmaxf(fmaf(sc1, t1.x, sh1), 0.f), fmaxf(fmaf(sc1, t1.y, sh1), 0.f),
                    fmaxf(fmaf(sc1, t1.z, sh1), 0.f), fmaxf(fmaf(sc1, t1.w, sh1), 0.f)};
#pragma unroll
    for (int j = 0; j < 4; j++) {
      m0 = fmaxf(m0, fmaxf(acc0[j] + tv0[j], 0.f));
      m1 = fmaxf(m1, fmaxf(acc1[j] + tv1[j], 0.f));
    }
  }
  part[kq * 64 + o0] = m0;
  part[kq * 64 + o0 + 1] = m1;
  __syncthreads();
  if (tid < 64) {
    float mm = part[tid];
    for (int g = 1; g < 8; g++) mm = fmaxf(mm, part[g * 64 + tid]);
    out1[((size_t)b * 64 + tid) * S_ + s] = mm;
  }
}

// ---------------------------------------------------------------------------
extern "C" void kernel_launch(void* const* d_in, const int* in_sizes, int n_in,
                              void* d_out, int out_size, void* d_ws, size_t ws_size,
                              hipStream_t stream) {
  const float* xyz = (const float*)d_in[0];
  const float* feature = (const float*)d_in[1];
  const float* alpha = (const float*)d_in[2];
  const float* beta = (const float*)d_in[3];
  const float* w_tr = (const float*)d_in[4];
  const float* b_tr = (const float*)d_in[5];
  const float* g_tr = (const float*)d_in[6];
  const float* be_tr = (const float*)d_in[7];
  const float* w1 = (const float*)d_in[8];
  const float* b1 = (const float*)d_in[9];
  const float* g1 = (const float*)d_in[10];
  const float* be1 = (const float*)d_in[11];
  const float* w2 = (const float*)d_in[12];
  const float* b2 = (const float*)d_in[13];

  char* ws = (char*)d_ws;
  int* fps_i = (int*)(ws);                      // 32768 B
  float* nxyz = (float*)(ws + 32768);           // 98304 B
  float* nfeat = (float*)(ws + 131072);         // 2097152 B
  int* knn = (int*)(ws + 2228224);              // 1048576 B
  float* stdpart = (float*)(ws + 3276800);      // 4096 B (fallback)
  float* invstd = (float*)(ws + 3280896);       // 64 B
  float* bn_tr = (float*)(ws + 3280960);        // 512 B
  float* bn_1 = (float*)(ws + 3281472);         // 512 B
  float* bnpart = (float*)(ws + 3281984);       // 4194304 B -> end 7476288
  float* featT = (float*)(ws + 7476288);        // 8388608 B
  float* dcache = (float*)(ws + 15864896);      // 71303168 B
  float* tcache = (float*)(ws + 87168064);      // 67108864 B
  float* ucache = (float*)(ws + 154276928);     // 67108864 B
  float* stdpart_c = (float*)(ws + 221385792);  // 8192 B -> total 221393984

  float* out0 = (float*)d_out;
  float* out1 = out0 + B_ * 3 * S_;

  const bool big = (ws_size >= 221393984ull);

  if (big) {
    // fps blocks 0..7 + 512 fused-transpose blocks
    fps_kernel<<<8 + 512, 256, 0, stream>>>(xyz, fps_i, nxyz, out0, feature, featT);
    // knn blocks 0..8191 + 2048 fused anchor-gather blocks
    knn_kernel<<<8192 + 2048, 256, 0, stream>>>(xyz, nxyz, knn, featT, fps_i, nfeat);
    prep_kernel<<<1024, 256, 0, stream>>>(featT, xyz, nxyz, nfeat, knn, dcache, stdpart_c);
    std_final_c<<<1, 64, 0, stream>>>(stdpart_c, invstd);
    mlp0c<<<B_ * S_, 256, 0, stream>>>(dcache, nfeat, invstd, alpha, beta, w_tr, b_tr,
                                       bnpart, tcache);
    bn_finalize<<<64, 256, 0, stream>>>(bnpart, g_tr, be_tr, bn_tr);
    mlp1c<<<B_ * S_, 256, 0, stream>>>(tcache, bn_tr, w1, b1, bnpart, ucache);
    bn_finalize<<<64, 256, 0, stream>>>(bnpart, g1, be1, bn_1);
    mlp2c<<<B_ * S_, 256, 0, stream>>>(tcache, ucache, bn_tr, bn_1, w2, b2, out1);
  } else {
    fps_kernel<<<8, 256, 0, stream>>>(xyz, fps_i, nxyz, out0, feature, featT);
    gather_nf<<<(B_ * S_ * D_) / 256, 256, 0, stream>>>(feature, fps_i, nfeat);
    knn_kernel<<<8192, 256, 0, stream>>>(xyz, nxyz, knn, nullptr, nullptr, nullptr);
    std_partial<<<B_ * 64, 256, 0, stream>>>(feature, xyz, nxyz, nfeat, knn, stdpart);
    std_final<<<1, 64, 0, stream>>>(stdpart, invstd);
    mlp_kernel<0><<<B_ * S_, 256, 0, stream>>>(feature, xyz, nxyz, nfeat, knn, invstd,
                                               alpha, beta, w_tr, b_tr, w1, b1, w2, b2,
                                               bn_tr, bn_1, bnpart, out1);
    bn_finalize<<<64, 256, 0, stream>>>(bnpart, g_tr, be_tr, bn_tr);
    mlp_kernel<1><<<B_ * S_, 256, 0, stream>>>(feature, xyz, nxyz, nfeat, knn, invstd,
                                               alpha, beta, w_tr, b_tr, w1, b1, w2, b2,
                                               bn_tr, bn_1, bnpart, out1);
    bn_finalize<<<64, 256, 0, stream>>>(bnpart, g1, be1, bn_1);
    mlp_kernel<2><<<B_ * S_, 256, 0, stream>>>(feature, xyz, nxyz, nfeat, knn, invstd,
                                               alpha, beta, w_tr, b_tr, w1, b1, w2, b2,
                                               bn_tr, bn_1, bnpart, out1);
  }
}

// Round 7
// 1136.872 us; speedup vs baseline: 1.8401x; 1.3525x over previous
//
#include <hip/hip_runtime.h>
#include <cfloat>
#include <math.h>

#define B_ 8
#define N_ 4096
#define D_ 64
#define S_ 1024
#define K_ 32
#define CIN_ 131  // 2*D + 3

typedef float f32x2 __attribute__((ext_vector_type(2)));

// Move a u64 across lanes with a constant DPP control (2x 32-bit update_dpp).
template <int CTRL>
__device__ __forceinline__ unsigned long long dpp_u64(unsigned long long k) {
  int lo = (int)(unsigned int)k, hi = (int)(unsigned int)(k >> 32);
  lo = __builtin_amdgcn_update_dpp(lo, lo, CTRL, 0xf, 0xf, false);
  hi = __builtin_amdgcn_update_dpp(hi, hi, CTRL, 0xf, 0xf, false);
  return ((unsigned long long)(unsigned int)hi << 32) | (unsigned int)lo;
}

// Wave(64)-wide float max via DPP (VALU pipe). Result broadcast via readlane 63.
__device__ __forceinline__ float wave_max_f32_dpp(float v) {
  int x = __float_as_int(v);
#define STEP(ctrl)                                                        \
  {                                                                       \
    int t = __builtin_amdgcn_update_dpp(x, x, ctrl, 0xf, 0xf, false);     \
    v = fmaxf(v, __int_as_float(t));                                      \
    x = __float_as_int(v);                                                \
  }
  STEP(0x111)
  STEP(0x112)
  STEP(0x114)
  STEP(0x118)
  STEP(0x142)
  STEP(0x143)
#undef STEP
  return __int_as_float(__builtin_amdgcn_readlane(x, 63));
}

// ---------------------------------------------------------------------------
// FPS (r2-validated, 585-589us): blocks 0..7, 256 thr, thread t owns
// [16t,16t+16). Packed f32x2 dist update (bit-exact IEEE, contract(off)),
// fmax tree local max, descending equality scan argmax, DPP wave max +
// ballot, 1 barrier, keyp LDS + 2-DPP u64 merge.
// SESSION LESSONS (do not retry):
//  - r4: 1-wave/64pt variant spills (256 f32 live state > VALU-addressable
//    VGPR) -> 1498us. Per-lane state must stay <~200 f32.
//  - fmax-chain+ballot is latency-optimal; u64-packed chain is slower
//    (longer dependent chain); speculative-coords just moves latency
//    across the barrier.
// Blocks 8..519 transpose feature [b][c][n] -> featT [b][n][c].
// ---------------------------------------------------------------------------
__global__ __launch_bounds__(256) void fps_kernel(const float* __restrict__ xyz,
                                                  int* __restrict__ fps_idx,
                                                  float* __restrict__ nxyz,
                                                  float* __restrict__ out0,
                                                  const float* __restrict__ feature,
                                                  float* __restrict__ featT) {
#pragma clang fp contract(off)
  const int tid = threadIdx.x;
  __shared__ __align__(16) float4 sp[N_];    // 64 KB coord mirror / transpose tile
  __shared__ int si[S_];
  __shared__ unsigned long long keyp[2][4];
  if (blockIdx.x >= 8) {
    // ---- fused transpose (validated r7 transpose_feat logic, 256 thr) ----
    const int blk = blockIdx.x - 8;
    const int b = blk >> 6, n0 = (blk & 63) * 64;
    float* tile = (float*)sp;  // 64*65 floats = 16.6 KB
#pragma unroll
    for (int i = 0; i < 16; i++) {
      int c = i * 4 + (tid >> 6), nl = tid & 63;
      tile[c * 65 + nl] = feature[((size_t)b * 64 + c) * N_ + n0 + nl];
    }
    __syncthreads();
#pragma unroll
    for (int i = 0; i < 16; i++) {
      int nl = i * 4 + (tid >> 6), c = tid & 63;
      featT[((size_t)b * N_ + n0 + nl) * 64 + c] = tile[c * 65 + nl];
    }
    return;
  }
  const int b = blockIdx.x;
  const float* xb = xyz + (size_t)b * 3 * N_;
  const float4* xv = (const float4*)xb;
  f32x2 pxv[8], pyv[8], pzv[8];
  float dist[16];
#pragma unroll
  for (int q = 0; q < 4; q++) {
    float4 X = xv[4 * tid + q];
    float4 Y = xv[1024 + 4 * tid + q];
    float4 Z = xv[2048 + 4 * tid + q];
    pxv[2 * q] = (f32x2){X.x, X.y};  pxv[2 * q + 1] = (f32x2){X.z, X.w};
    pyv[2 * q] = (f32x2){Y.x, Y.y};  pyv[2 * q + 1] = (f32x2){Y.z, Y.w};
    pzv[2 * q] = (f32x2){Z.x, Z.y};  pzv[2 * q + 1] = (f32x2){Z.z, Z.w};
  }
#pragma unroll
  for (int j = 0; j < 8; j++) {
    dist[2 * j] = 1e10f;
    dist[2 * j + 1] = 1e10f;
    sp[16 * tid + 2 * j] = make_float4(pxv[j].x, pyv[j].x, pzv[j].x, 0.f);
    sp[16 * tid + 2 * j + 1] = make_float4(pxv[j].y, pyv[j].y, pzv[j].y, 0.f);
  }
  if (tid == 0) si[0] = 0;
  __syncthreads();
  float cx = sp[0].x, cy = sp[0].y, cz = sp[0].z;
  const int wav = tid >> 6, lane = tid & 63;
  for (int s = 1; s < S_; s++) {
    // --- packed dist update (exact: pk lanes are independent IEEE ops,
    //     same op order (dx*dx + dy*dy) + dz*dz as validated rounds) ---
    const f32x2 c2x = {cx, cx}, c2y = {cy, cy}, c2z = {cz, cz};
#pragma unroll
    for (int j = 0; j < 8; j++) {
      f32x2 dx = pxv[j] - c2x;
      f32x2 dy = pyv[j] - c2y;
      f32x2 dz = pzv[j] - c2z;
      f32x2 d = (dx * dx + dy * dy) + dz * dz;
      dist[2 * j] = fminf(dist[2 * j], d.x);
      dist[2 * j + 1] = fminf(dist[2 * j + 1], d.y);
    }
    // --- local max via fmax tree (order-independent, exact) ---
    float t8[8], t4[4];
#pragma unroll
    for (int j = 0; j < 8; j++) t8[j] = fmaxf(dist[2 * j], dist[2 * j + 1]);
#pragma unroll
    for (int j = 0; j < 4; j++) t4[j] = fmaxf(t8[2 * j], t8[2 * j + 1]);
    float best = fmaxf(fmaxf(t4[0], t4[1]), fmaxf(t4[2], t4[3]));
    // --- local argmax: descending equality scan -> first (smallest) index
    //     with dist == best; identical tie-break to strict-> ascending scan ---
    int bi = 16 * tid;
#pragma unroll
    for (int i = 15; i >= 0; i--)
      if (dist[i] == best) bi = 16 * tid + i;
    float wmax = wave_max_f32_dpp(best);
    unsigned long long m = __ballot(best == wmax);
    int l = __ffsll(m) - 1;
    int widx = __builtin_amdgcn_readlane(bi, l);
    if (lane == 0)
      keyp[s & 1][wav] =
          ((unsigned long long)(unsigned int)__float_as_int(wmax) << 32) |
          (unsigned int)(4095 - widx);
    __syncthreads();
    // merge 4 per-wave winners: 1 LDS read + 2 DPP steps (period-4 in quads)
    unsigned long long k = keyp[s & 1][lane & 3];
    unsigned long long t;
    t = dpp_u64<0xB1>(k); if (t > k) k = t;  // quad_perm xor 1
    t = dpp_u64<0x4E>(k); if (t > k) k = t;  // quad_perm xor 2
    int bix = 4095 - (int)(k & 0xfffull);
    if (tid == 0) si[s] = bix;
    float4 c = sp[bix];
    cx = c.x; cy = c.y; cz = c.z;
  }
  __syncthreads();
  for (int e = tid; e < S_; e += 256) {
    int n = si[e];
    fps_idx[b * S_ + e] = n;
    float4 c = sp[n];
    nxyz[(size_t)(b * S_ + e) * 3 + 0] = c.x;
    nxyz[(size_t)(b * S_ + e) * 3 + 1] = c.y;
    nxyz[(size_t)(b * S_ + e) * 3 + 2] = c.z;
    out0[(size_t)b * 3 * S_ + e] = c.x;
    out0[(size_t)b * 3 * S_ + S_ + e] = c.y;
    out0[(size_t)b * 3 * S_ + 2 * S_ + e] = c.z;
  }
}

// ---------------------------------------------------------------------------
// kNN (validated r2). Packed f32x2 distance init, selection logic unchanged.
// Blocks >= 8192 perform the fused anchor-feature gather from featT.
// ---------------------------------------------------------------------------
__global__ __launch_bounds__(256) void knn_kernel(const float* __restrict__ xyz,
                                                  const float* __restrict__ nxyz,
                                                  int* __restrict__ knn,
                                                  const float* __restrict__ featT,
                                                  const int* __restrict__ fps_i,
                                                  float* __restrict__ nfeat) {
#pragma clang fp contract(off)
  const int bs = blockIdx.x, tid = threadIdx.x;
  if (bs >= 8192) {
    int e = (bs - 8192) * 256 + tid;  // < B*S*D
    int bsx = e >> 6, c = e & 63;
    int bq = bsx >> 10;
    int n = fps_i[bsx];
    nfeat[e] = featT[((size_t)bq * N_ + n) * 64 + c];
    return;
  }
  const int b = bs >> 10;
  const float* xb = xyz + (size_t)b * 3 * N_;
  const float cx = nxyz[(size_t)bs * 3], cy = nxyz[(size_t)bs * 3 + 1], cz = nxyz[(size_t)bs * 3 + 2];
  const float cn = (cx * cx + cy * cy) + cz * cz;
  const f32x2 c2x = {cx, cx}, c2y = {cy, cy}, c2z = {cz, cz};
  const f32x2 c2n = {cn, cn}, two = {2.0f, 2.0f};
  float d[16];
#pragma unroll
  for (int j = 0; j < 8; j++) {
    int n0 = (2 * j) * 256 + tid, n1 = n0 + 256;
    f32x2 px = {xb[n0], xb[n1]};
    f32x2 py = {xb[N_ + n0], xb[N_ + n1]};
    f32x2 pz = {xb[2 * N_ + n0], xb[2 * N_ + n1]};
    f32x2 pn = (px * px + py * py) + pz * pz;
    f32x2 dot = (c2x * px + c2y * py) + c2z * pz;
    f32x2 dd = (c2n + pn) - two * dot;
    d[2 * j] = dd.x;
    d[2 * j + 1] = dd.y;
  }
  float mv = FLT_MAX;
  int mi = tid;
#pragma unroll
  for (int i = 0; i < 16; i++)
    if (d[i] < mv) { mv = d[i]; mi = i * 256 + tid; }
  __shared__ unsigned long long keyp[2][4];
  __shared__ int skk[K_];
  const int wav = tid >> 6, lane = tid & 63;
  for (int j = 0; j < K_; j++) {
    unsigned int u = __float_as_uint(mv);
    u ^= ((unsigned int)((int)u >> 31) | 0x80000000u);
    unsigned long long key = ((unsigned long long)u << 32) | (unsigned int)mi;
#pragma unroll
    for (int off = 32; off >= 1; off >>= 1) {
      unsigned long long ok = __shfl_xor(key, off);
      if (ok < key) key = ok;
    }
    if (lane == 0) keyp[j & 1][wav] = key;
    __syncthreads();
    unsigned long long kmin = keyp[j & 1][0];
#pragma unroll
    for (int w = 1; w < 4; w++) {
      unsigned long long k2 = keyp[j & 1][w];
      if (k2 < kmin) kmin = k2;
    }
    int g = (int)(kmin & 0xffffffffull);
    if (tid == 0) skk[j] = g;
    if ((g & 255) == tid) {
      int sl = g >> 8;
#pragma unroll
      for (int i = 0; i < 16; i++)
        if (i == sl) d[i] = FLT_MAX;
      mv = FLT_MAX; mi = tid;
#pragma unroll
      for (int i = 0; i < 16; i++)
        if (d[i] < mv) { mv = d[i]; mi = i * 256 + tid; }
    }
  }
  __syncthreads();
  if (tid < K_) knn[(size_t)bs * K_ + tid] = skk[tid];
}

// ===========================================================================
// ============ FALLBACK (r6) kernels — used when ws is small ================
// ===========================================================================
__global__ __launch_bounds__(256) void gather_nf(const float* __restrict__ feature,
                                                 const int* __restrict__ fps_i,
                                                 float* __restrict__ nfeat) {
  int e = blockIdx.x * 256 + threadIdx.x;
  int b = e >> 16, rem = e & 65535;
  int s = rem >> 6, c = rem & 63;
  int n = fps_i[b * S_ + s];
  nfeat[e] = feature[((size_t)b * 64 + c) * N_ + n];
}

__global__ __launch_bounds__(256) void std_partial(const float* __restrict__ feature,
                                                   const float* __restrict__ xyz,
                                                   const float* __restrict__ nxyz,
                                                   const float* __restrict__ nfeat,
                                                   const int* __restrict__ knn,
                                                   float* __restrict__ outp) {
  const int blk = blockIdx.x, tid = threadIdx.x;
  const int b = blk >> 6, chunk = blk & 63;
  float s = 0.f, q = 0.f;
  for (int e = tid; e < 16 * K_ * 67; e += 256) {
    int so = e / (K_ * 67);
    int rem = e - so * (K_ * 67);
    int kk = rem / 67;
    int c = rem - kk * 67;
    int bs = b * S_ + chunk * 16 + so;
    int n = knn[(size_t)bs * K_ + kk];
    float raw = (c < 64) ? feature[((size_t)b * 64 + c) * N_ + n]
                         : xyz[((size_t)b * 3 + (c - 64)) * N_ + n];
    float anc = (c < 64) ? nfeat[(size_t)bs * 64 + c]
                         : nxyz[(size_t)bs * 3 + (c - 64)];
    float dd = raw - anc;
    s += dd; q += dd * dd;
  }
#pragma unroll
  for (int off = 32; off >= 1; off >>= 1) { s += __shfl_xor(s, off); q += __shfl_xor(q, off); }
  __shared__ float rs[4], rq[4];
  if ((tid & 63) == 0) { rs[tid >> 6] = s; rq[tid >> 6] = q; }
  __syncthreads();
  if (tid == 0) {
    outp[blk * 2] = rs[0] + rs[1] + rs[2] + rs[3];
    outp[blk * 2 + 1] = rq[0] + rq[1] + rq[2] + rq[3];
  }
}

__global__ void std_final(const float* __restrict__ part, float* __restrict__ invstd) {
  int b = threadIdx.x;
  if (b < B_) {
    double s = 0.0, q = 0.0;
    for (int i = 0; i < 64; i++) {
      s += (double)part[(b * 64 + i) * 2];
      q += (double)part[(b * 64 + i) * 2 + 1];
    }
    const double n = (double)(S_ * K_ * 67);
    double var = (q - s * s / n) / (n - 1.0);
    invstd[b] = (float)(1.0 / (sqrt(var) + 1e-5));
  }
}

template <int MODE>
__global__ __launch_bounds__(256, 2) void mlp_kernel(
    const float* __restrict__ feature, const float* __restrict__ xyz,
    const float* __restrict__ nxyz, const float* __restrict__ nfeat,
    const int* __restrict__ knn, const float* __restrict__ invstd,
    const float* __restrict__ alpha, const float* __restrict__ beta,
    const float* __restrict__ w_tr, const float* __restrict__ b_tr,
    const float* __restrict__ w1, const float* __restrict__ b1,
    const float* __restrict__ w2, const float* __restrict__ b2,
    const float* __restrict__ bn_tr, const float* __restrict__ bn_1,
    float* __restrict__ bnpart, float* __restrict__ out1) {
  __shared__ __align__(16) float pool[15556];
  float* Wt = pool;
  float* xin = pool + 8516;
  float* ub = xin;
  float* tb = pool + 8516 + 4192;
  float* part = pool + 8516 + 4192 + 2304;
  int* sknn = (int*)(part + 512);
  const int bs = blockIdx.x, tid = threadIdx.x;
  const int b = bs >> 10, s = bs & 1023;
  if (tid < K_) sknn[tid] = knn[(size_t)bs * K_ + tid];
  for (int e = tid; e < 64 * 131; e += 256) {
    int o = e / 131, c = e - o * 131;
    Wt[c * 65 + o] = w_tr[e];
  }
  __syncthreads();
  const float inv = invstd[b];
  for (int e = tid; e < CIN_ * K_; e += 256) {
    int c = e >> 5, kk = e & 31;
    float v;
    if (c < 67) {
      int n = sknn[kk];
      float raw = (c < 64) ? feature[((size_t)b * 64 + c) * N_ + n]
                           : xyz[((size_t)b * 3 + (c - 64)) * N_ + n];
      float anc = (c < 64) ? nfeat[(size_t)bs * 64 + c]
                           : nxyz[(size_t)bs * 3 + (c - 64)];
      v = alpha[c] * ((raw - anc) * inv) + beta[c];
    } else {
      v = nfeat[(size_t)bs * 64 + (c - 67)];
    }
    xin[e] = v;
  }
  __syncthreads();
  const int o = tid & 63, kkb = (tid >> 6) * 8;
  float acc[8];
  {
    float bv = b_tr[o];
#pragma unroll
    for (int j = 0; j < 8; j++) acc[j] = bv;
  }
  for (int c = 0; c < CIN_; c++) {
    float w = Wt[c * 65 + o];
    const float4 xa = *(const float4*)(xin + c * 32 + kkb);
    const float4 xb4 = *(const float4*)(xin + c * 32 + kkb + 4);
    acc[0] += w * xa.x; acc[1] += w * xa.y; acc[2] += w * xa.z; acc[3] += w * xa.w;
    acc[4] += w * xb4.x; acc[5] += w * xb4.y; acc[6] += w * xb4.z; acc[7] += w * xb4.w;
  }
  if (MODE == 0) {
    float s8 = 0.f, q8 = 0.f;
#pragma unroll
    for (int j = 0; j < 8; j++) { s8 += acc[j]; q8 += acc[j] * acc[j]; }
    part[(tid >> 6) * 64 + o] = s8;
    part[256 + (tid >> 6) * 64 + o] = q8;
    __syncthreads();
    if (tid < 64) {
      float ss = 0.f, qq = 0.f;
      for (int g = 0; g < 4; g++) { ss += part[g * 64 + tid]; qq += part[256 + g * 64 + tid]; }
      bnpart[(size_t)bs * 128 + tid] = ss;
      bnpart[(size_t)bs * 128 + 64 + tid] = qq;
    }
    return;
  }
  float tv[8];
  {
    float sc = bn_tr[o], sh = bn_tr[64 + o];
#pragma unroll
    for (int j = 0; j < 8; j++) {
      tv[j] = fmaxf(fmaf(sc, acc[j], sh), 0.f);
      tb[o * 36 + kkb + j] = tv[j];
    }
  }
  __syncthreads();
  for (int e = tid; e < 64 * 64; e += 256) {
    int oo = e >> 6, c = e & 63;
    Wt[c * 65 + oo] = w1[e];
  }
  __syncthreads();
  float acc2[8];
  {
    float bv = b1[o];
#pragma unroll
    for (int j = 0; j < 8; j++) acc2[j] = bv;
  }
  for (int c = 0; c < 64; c++) {
    float w = Wt[c * 65 + o];
    const float4 ta = *(const float4*)(tb + c * 36 + kkb);
    const float4 ta2 = *(const float4*)(tb + c * 36 + kkb + 4);
    acc2[0] += w * ta.x; acc2[1] += w * ta.y; acc2[2] += w * ta.z; acc2[3] += w * ta.w;
    acc2[4] += w * ta2.x; acc2[5] += w * ta2.y; acc2[6] += w * ta2.z; acc2[7] += w * ta2.w;
  }
  if (MODE == 1) {
    float s8 = 0.f, q8 = 0.f;
#pragma unroll
    for (int j = 0; j < 8; j++) { s8 += acc2[j]; q8 += acc2[j] * acc2[j]; }
    part[(tid >> 6) * 64 + o] = s8;
    part[256 + (tid >> 6) * 64 + o] = q8;
    __syncthreads();
    if (tid < 64) {
      float ss = 0.f, qq = 0.f;
      for (int g = 0; g < 4; g++) { ss += part[g * 64 + tid]; qq += part[256 + g * 64 + tid]; }
      bnpart[(size_t)bs * 128 + tid] = ss;
      bnpart[(size_t)bs * 128 + 64 + tid] = qq;
    }
    return;
  }
  {
    float sc = bn_1[o], sh = bn_1[64 + o];
#pragma unroll
    for (int j = 0; j < 8; j++) ub[o * 36 + kkb + j] = fmaxf(fmaf(sc, acc2[j], sh), 0.f);
  }
  __syncthreads();
  for (int e = tid; e < 64 * 64; e += 256) {
    int oo = e >> 6, c = e & 63;
    Wt[c * 65 + oo] = w2[e];
  }
  __syncthreads();
  float acc3[8];
  {
    float bv = b2[o];
#pragma unroll
    for (int j = 0; j < 8; j++) acc3[j] = bv;
  }
  for (int c = 0; c < 64; c++) {
    float w = Wt[c * 65 + o];
    const float4 ua = *(const float4*)(ub + c * 36 + kkb);
    const float4 ua2 = *(const float4*)(ub + c * 36 + kkb + 4);
    acc3[0] += w * ua.x; acc3[1] += w * ua.y; acc3[2] += w * ua.z; acc3[3] += w * ua.w;
    acc3[4] += w * ua2.x; acc3[5] += w * ua2.y; acc3[6] += w * ua2.z; acc3[7] += w * ua2.w;
  }
  float m = 0.f;
#pragma unroll
  for (int j = 0; j < 8; j++) m = fmaxf(m, fmaxf(acc3[j] + tv[j], 0.f));
  part[(tid >> 6) * 64 + o] = m;
  __syncthreads();
  if (tid < 64) {
    float mm = part[tid];
    for (int g = 1; g < 4; g++) mm = fmaxf(mm, part[g * 64 + tid]);
    out1[((size_t)b * 64 + tid) * S_ + s] = mm;
  }
}

// ---------------------------------------------------------------------------
// BN finalize (shared by both paths).
// ---------------------------------------------------------------------------
__global__ __launch_bounds__(256) void bn_finalize(const float* __restrict__ part,
                                                   const float* __restrict__ g,
                                                   const float* __restrict__ be,
                                                   float* __restrict__ bnout) {
  const int ch = blockIdx.x, tid = threadIdx.x;
  double s = 0.0, q = 0.0;
  for (int i = tid; i < B_ * S_; i += 256) {
    s += (double)part[(size_t)i * 128 + ch];
    q += (double)part[(size_t)i * 128 + 64 + ch];
  }
#pragma unroll
  for (int off = 32; off >= 1; off >>= 1) { s += __shfl_xor(s, off); q += __shfl_xor(q, off); }
  __shared__ double ls[4], lq[4];
  if ((tid & 63) == 0) { ls[tid >> 6] = s; lq[tid >> 6] = q; }
  __syncthreads();
  if (tid == 0) {
    double Ssum = ls[0] + ls[1] + ls[2] + ls[3];
    double Qsum = lq[0] + lq[1] + lq[2] + lq[3];
    const double n = (double)(B_ * S_ * K_);
    double mu = Ssum / n;
    double var = Qsum / n - mu * mu;
    double sc = (double)g[ch] / sqrt(var + 1e-5);
    bnout[ch] = (float)sc;
    bnout[64 + ch] = (float)((double)be[ch] - mu * sc);
  }
}

// ===========================================================================
// ================== CACHE-PATH kernels (large workspace) ===================
// ===========================================================================

// Fused diff computation + std partials. 1024 blocks x 8 groups.
__global__ __launch_bounds__(256) void prep_kernel(const float* __restrict__ featT,
                                                   const float* __restrict__ xyz,
                                                   const float* __restrict__ nxyz,
                                                   const float* __restrict__ nfeat,
                                                   const int* __restrict__ knn,
                                                   float* __restrict__ dcache,
                                                   float* __restrict__ outp) {
  const int blk = blockIdx.x, tid = threadIdx.x;
  __shared__ int sk[32];
  float s = 0.f, q = 0.f;
  const int c = tid & 63, qd = tid >> 6;
  for (int g = 0; g < 8; g++) {
    const int bs = blk * 8 + g, b = bs >> 10;
    if (tid < 32) sk[tid] = knn[(size_t)bs * K_ + tid];
    __syncthreads();
    float anc = nfeat[(size_t)bs * 64 + c];
#pragma unroll
    for (int it = 0; it < 8; it++) {
      int kk = it * 4 + qd;
      int n = sk[kk];
      float dd = featT[((size_t)b * N_ + n) * 64 + c] - anc;
      s += dd; q += dd * dd;
      dcache[((size_t)bs * 32 + kk) * 68 + c] = dd;
    }
    if (tid < 96) {
      int c3 = tid >> 5, kk = tid & 31;
      int n = sk[kk];
      float dd = xyz[((size_t)b * 3 + c3) * N_ + n] - nxyz[(size_t)bs * 3 + c3];
      s += dd; q += dd * dd;
      dcache[((size_t)bs * 32 + kk) * 68 + 64 + c3] = dd;
    }
    __syncthreads();
  }
#pragma unroll
  for (int off = 32; off >= 1; off >>= 1) { s += __shfl_xor(s, off); q += __shfl_xor(q, off); }
  __shared__ float rs[4], rq[4];
  if ((tid & 63) == 0) { rs[tid >> 6] = s; rq[tid >> 6] = q; }
  __syncthreads();
  if (tid == 0) {
    outp[blk * 2] = rs[0] + rs[1] + rs[2] + rs[3];
    outp[blk * 2 + 1] = rq[0] + rq[1] + rq[2] + rq[3];
  }
}

__global__ void std_final_c(const float* __restrict__ part, float* __restrict__ invstd) {
  int b = threadIdx.x;
  if (b < B_) {
    double s = 0.0, q = 0.0;
    for (int i = 0; i < 128; i++) {
      s += (double)part[(b * 128 + i) * 2];
      q += (double)part[(b * 128 + i) * 2 + 1];
    }
    const double n = (double)(S_ * K_ * 67);
    double var = (q - s * s / n) / (n - 1.0);
    invstd[b] = (float)(1.0 / (sqrt(var) + 1e-5));
  }
}

// MLP stage 0: xin from dcache (coalesced), conv_tr, stats + tcache store.
// r6 LESSON: keep o=tid&63, kkb=(tid>>6)*8 — kkb is WAVE-UNIFORM so the two
// float4 xin reads are LDS broadcasts (near-free) and Wt stride-65 b32 is
// 2-way-aliased (free). The 2o×4k "fewer LDS instr" tile broke the broadcast
// property and cost +397us across the chain (r3/r6 measured). Do not retile.
__global__ __launch_bounds__(256, 2) void mlp0c(
    const float* __restrict__ dcache, const float* __restrict__ nfeat,
    const float* __restrict__ invstd,
    const float* __restrict__ alpha, const float* __restrict__ beta,
    const float* __restrict__ w_tr, const float* __restrict__ b_tr,
    float* __restrict__ bnpart, float* __restrict__ tcache) {
  __shared__ __align__(16) float pool[13220];
  float* Wt = pool;
  float* xin = pool + 8516;
  float* part = pool + 8516 + 4192;
  const int bs = blockIdx.x, tid = threadIdx.x;
  const int b = bs >> 10;
  for (int e = tid; e < 64 * 131; e += 256) {
    int o = e / 131, c = e - o * 131;
    Wt[c * 65 + o] = w_tr[e];
  }
  const float inv = invstd[b];
  {
    const int c = tid & 63, qd = tid >> 6;
    float al = alpha[c], bev = beta[c];
#pragma unroll
    for (int it = 0; it < 8; it++) {
      int kk = it * 4 + qd;
      xin[c * 32 + kk] = al * (dcache[((size_t)bs * 32 + kk) * 68 + c] * inv) + bev;
    }
    if (tid < 96) {
      int c3 = 64 + (tid >> 5), kk = tid & 31;
      xin[c3 * 32 + kk] =
          alpha[c3] * (dcache[((size_t)bs * 32 + kk) * 68 + c3] * inv) + beta[c3];
    }
    for (int e = tid; e < 2048; e += 256) {
      int cc = 67 + (e >> 5), kk = e & 31;
      xin[cc * 32 + kk] = nfeat[(size_t)bs * 64 + (e >> 5)];
    }
  }
  __syncthreads();
  const int o = tid & 63, kkb = (tid >> 6) * 8;
  float acc[8];
  {
    float bv = b_tr[o];
#pragma unroll
    for (int j = 0; j < 8; j++) acc[j] = bv;
  }
  for (int c = 0; c < CIN_; c++) {
    float w = Wt[c * 65 + o];
    const float4 xa = *(const float4*)(xin + c * 32 + kkb);
    const float4 xb4 = *(const float4*)(xin + c * 32 + kkb + 4);
    acc[0] += w * xa.x; acc[1] += w * xa.y; acc[2] += w * xa.z; acc[3] += w * xa.w;
    acc[4] += w * xb4.x; acc[5] += w * xb4.y; acc[6] += w * xb4.z; acc[7] += w * xb4.w;
  }
  {
    float4* tp = (float4*)(tcache + ((size_t)bs * 64 + o) * 32 + kkb);
    tp[0] = make_float4(acc[0], acc[1], acc[2], acc[3]);
    tp[1] = make_float4(acc[4], acc[5], acc[6], acc[7]);
  }
  float s8 = 0.f, q8 = 0.f;
#pragma unroll
  for (int j = 0; j < 8; j++) { s8 += acc[j]; q8 += acc[j] * acc[j]; }
  part[(tid >> 6) * 64 + o] = s8;
  part[256 + (tid >> 6) * 64 + o] = q8;
  __syncthreads();
  if (tid < 64) {
    float ss = 0.f, qq = 0.f;
    for (int g = 0; g < 4; g++) { ss += part[g * 64 + tid]; qq += part[256 + g * 64 + tid]; }
    bnpart[(size_t)bs * 128 + tid] = ss;
    bnpart[(size_t)bs * 128 + 64 + tid] = qq;
  }
}

// MLP stage 1: t = bn+relu(tcache); conv1; stats + ucache store.
__global__ __launch_bounds__(256, 3) void mlp1c(
    const float* __restrict__ tcache, const float* __restrict__ bn_tr,
    const float* __restrict__ w1, const float* __restrict__ b1,
    float* __restrict__ bnpart, float* __restrict__ ucache) {
  __shared__ __align__(16) float pool[6976];
  float* Wt = pool;
  float* tb = pool + 4160;
  float* part = pool + 4160 + 2304;
  const int bs = blockIdx.x, tid = threadIdx.x;
  const int o = tid & 63, kkb = (tid >> 6) * 8;
  for (int e = tid; e < 64 * 64; e += 256) {
    int oo = e >> 6, c = e & 63;
    Wt[c * 65 + oo] = w1[e];
  }
  float t[8];
  {
    const float4* tp = (const float4*)(tcache + ((size_t)bs * 64 + o) * 32 + kkb);
    float4 a = tp[0], b4 = tp[1];
    t[0] = a.x; t[1] = a.y; t[2] = a.z; t[3] = a.w;
    t[4] = b4.x; t[5] = b4.y; t[6] = b4.z; t[7] = b4.w;
  }
  {
    float sc = bn_tr[o], sh = bn_tr[64 + o];
#pragma unroll
    for (int j = 0; j < 8; j++) tb[o * 36 + kkb + j] = fmaxf(fmaf(sc, t[j], sh), 0.f);
  }
  __syncthreads();
  float acc2[8];
  {
    float bv = b1[o];
#pragma unroll
    for (int j = 0; j < 8; j++) acc2[j] = bv;
  }
  for (int c = 0; c < 64; c++) {
    float w = Wt[c * 65 + o];
    const float4 ta = *(const float4*)(tb + c * 36 + kkb);
    const float4 ta2 = *(const float4*)(tb + c * 36 + kkb + 4);
    acc2[0] += w * ta.x; acc2[1] += w * ta.y; acc2[2] += w * ta.z; acc2[3] += w * ta.w;
    acc2[4] += w * ta2.x; acc2[5] += w * ta2.y; acc2[6] += w * ta2.z; acc2[7] += w * ta2.w;
  }
  {
    float4* up = (float4*)(ucache + ((size_t)bs * 64 + o) * 32 + kkb);
    up[0] = make_float4(acc2[0], acc2[1], acc2[2], acc2[3]);
    up[1] = make_float4(acc2[4], acc2[5], acc2[6], acc2[7]);
  }
  float s8 = 0.f, q8 = 0.f;
#pragma unroll
  for (int j = 0; j < 8; j++) { s8 += acc2[j]; q8 += acc2[j] * acc2[j]; }
  part[(tid >> 6) * 64 + o] = s8;
  part[256 + (tid >> 6) * 64 + o] = q8;
  __syncthreads();
  if (tid < 64) {
    float ss = 0.f, qq = 0.f;
    for (int g = 0; g < 4; g++) { ss += part[g * 64 + tid]; qq += part[256 + g * 64 + tid]; }
    bnpart[(size_t)bs * 128 + tid] = ss;
    bnpart[(size_t)bs * 128 + 64 + tid] = qq;
  }
}

// MLP stage 2: u = bn+relu(ucache); conv2; residual with bn+relu(tcache); max.
__global__ __launch_bounds__(256, 3) void mlp2c(
    const float* __restrict__ tcache, const float* __restrict__ ucache,
    const float* __restrict__ bn_tr, const float* __restrict__ bn_1,
    const float* __restrict__ w2, const float* __restrict__ b2,
    float* __restrict__ out1) {
  __shared__ __align__(16) float pool[6976];
  float* Wt = pool;
  float* ub = pool + 4160;
  float* part = pool + 4160 + 2304;
  const int bs = blockIdx.x, tid = threadIdx.x;
  const int b = bs >> 10, s = bs & 1023;
  const int o = tid & 63, kkb = (tid >> 6) * 8;
  for (int e = tid; e < 64 * 64; e += 256) {
    int oo = e >> 6, c = e & 63;
    Wt[c * 65 + oo] = w2[e];
  }
  {
    const float4* up = (const float4*)(ucache + ((size_t)bs * 64 + o) * 32 + kkb);
    float4 a = up[0], b4 = up[1];
    float u[8] = {a.x, a.y, a.z, a.w, b4.x, b4.y, b4.z, b4.w};
    float sc = bn_1[o], sh = bn_1[64 + o];
#pragma unroll
    for (int j = 0; j < 8; j++) ub[o * 36 + kkb + j] = fmaxf(fmaf(sc, u[j], sh), 0.f);
  }
  __syncthreads();
  float acc3[8];
  {
    float bv = b2[o];
#pragma unroll
    for (int j = 0; j < 8; j++) acc3[j] = bv;
  }
  for (int c = 0; c < 64; c++) {
    float w = Wt[c * 65 + o];
    const float4 ua = *(const float4*)(ub + c * 36 + kkb);
    const float4 ua2 = *(const float4*)(ub + c * 36 + kkb + 4);
    acc3[0] += w * ua.x; acc3[1] += w * ua.y; acc3[2] += w * ua.z; acc3[3] += w * ua.w;
    acc3[4] += w * ua2.x; acc3[5] += w * ua2.y; acc3[6] += w * ua2.z; acc3[7] += w * ua2.w;
  }
  float tv[8];
  {
    const float4* tp = (const float4*)(tcache + ((size_t)bs * 64 + o) * 32 + kkb);
    float4 a = tp[0], b4 = tp[1];
    float t[8] = {a.x, a.y, a.z, a.w, b4.x, b4.y, b4.z, b4.w};
    float sc = bn_tr[o], sh = bn_tr[64 + o];
#pragma unroll
    for (int j = 0; j < 8; j++) tv[j] = fmaxf(fmaf(sc, t[j], sh), 0.f);
  }
  float m = 0.f;
#pragma unroll
  for (int j = 0; j < 8; j++) m = fmaxf(m, fmaxf(acc3[j] + tv[j], 0.f));
  part[(tid >> 6) * 64 + o] = m;
  __syncthreads();
  if (tid < 64) {
    float mm = part[tid];
    for (int g = 1; g < 4; g++) mm = fmaxf(mm, part[g * 64 + tid]);
    out1[((size_t)b * 64 + tid) * S_ + s] = mm;
  }
}

// ---------------------------------------------------------------------------
extern "C" void kernel_launch(void* const* d_in, const int* in_sizes, int n_in,
                              void* d_out, int out_size, void* d_ws, size_t ws_size,
                              hipStream_t stream) {
  const float* xyz = (const float*)d_in[0];
  const float* feature = (const float*)d_in[1];
  const float* alpha = (const float*)d_in[2];
  const float* beta = (const float*)d_in[3];
  const float* w_tr = (const float*)d_in[4];
  const float* b_tr = (const float*)d_in[5];
  const float* g_tr = (const float*)d_in[6];
  const float* be_tr = (const float*)d_in[7];
  const float* w1 = (const float*)d_in[8];
  const float* b1 = (const float*)d_in[9];
  const float* g1 = (const float*)d_in[10];
  const float* be1 = (const float*)d_in[11];
  const float* w2 = (const float*)d_in[12];
  const float* b2 = (const float*)d_in[13];

  char* ws = (char*)d_ws;
  int* fps_i = (int*)(ws);                      // 32768 B
  float* nxyz = (float*)(ws + 32768);           // 98304 B
  float* nfeat = (float*)(ws + 131072);         // 2097152 B
  int* knn = (int*)(ws + 2228224);              // 1048576 B
  float* stdpart = (float*)(ws + 3276800);      // 4096 B (fallback)
  float* invstd = (float*)(ws + 3280896);       // 64 B
  float* bn_tr = (float*)(ws + 3280960);        // 512 B
  float* bn_1 = (float*)(ws + 3281472);         // 512 B
  float* bnpart = (float*)(ws + 3281984);       // 4194304 B -> end 7476288
  float* featT = (float*)(ws + 7476288);        // 8388608 B
  float* dcache = (float*)(ws + 15864896);      // 71303168 B
  float* tcache = (float*)(ws + 87168064);      // 67108864 B
  float* ucache = (float*)(ws + 154276928);     // 67108864 B
  float* stdpart_c = (float*)(ws + 221385792);  // 8192 B -> total 221393984

  float* out0 = (float*)d_out;
  float* out1 = out0 + B_ * 3 * S_;

  const bool big = (ws_size >= 221393984ull);

  if (big) {
    // fps blocks 0..7 + 512 fused-transpose blocks
    fps_kernel<<<8 + 512, 256, 0, stream>>>(xyz, fps_i, nxyz, out0, feature, featT);
    // knn blocks 0..8191 + 2048 fused anchor-gather blocks
    knn_kernel<<<8192 + 2048, 256, 0, stream>>>(xyz, nxyz, knn, featT, fps_i, nfeat);
    prep_kernel<<<1024, 256, 0, stream>>>(featT, xyz, nxyz, nfeat, knn, dcache, stdpart_c);
    std_final_c<<<1, 64, 0, stream>>>(stdpart_c, invstd);
    mlp0c<<<B_ * S_, 256, 0, stream>>>(dcache, nfeat, invstd, alpha, beta, w_tr, b_tr,
                                       bnpart, tcache);
    bn_finalize<<<64, 256, 0, stream>>>(bnpart, g_tr, be_tr, bn_tr);
    mlp1c<<<B_ * S_, 256, 0, stream>>>(tcache, bn_tr, w1, b1, bnpart, ucache);
    bn_finalize<<<64, 256, 0, stream>>>(bnpart, g1, be1, bn_1);
    mlp2c<<<B_ * S_, 256, 0, stream>>>(tcache, ucache, bn_tr, bn_1, w2, b2, out1);
  } else {
    fps_kernel<<<8, 256, 0, stream>>>(xyz, fps_i, nxyz, out0, feature, featT);
    gather_nf<<<(B_ * S_ * D_) / 256, 256, 0, stream>>>(feature, fps_i, nfeat);
    knn_kernel<<<8192, 256, 0, stream>>>(xyz, nxyz, knn, nullptr, nullptr, nullptr);
    std_partial<<<B_ * 64, 256, 0, stream>>>(feature, xyz, nxyz, nfeat, knn, stdpart);
    std_final<<<1, 64, 0, stream>>>(stdpart, invstd);
    mlp_kernel<0><<<B_ * S_, 256, 0, stream>>>(feature, xyz, nxyz, nfeat, knn, invstd,
                                               alpha, beta, w_tr, b_tr, w1, b1, w2, b2,
                                               bn_tr, bn_1, bnpart, out1);
    bn_finalize<<<64, 256, 0, stream>>>(bnpart, g_tr, be_tr, bn_tr);
    mlp_kernel<1><<<B_ * S_, 256, 0, stream>>>(feature, xyz, nxyz, nfeat, knn, invstd,
                                               alpha, beta, w_tr, b_tr, w1, b1, w2, b2,
                                               bn_tr, bn_1, bnpart, out1);
    bn_finalize<<<64, 256, 0, stream>>>(bnpart, g1, be1, bn_1);
    mlp_kernel<2><<<B_ * S_, 256, 0, stream>>>(feature, xyz, nxyz, nfeat, knn, invstd,
                                               alpha, beta, w_tr, b_tr, w1, b1, w2, b2,
                                               bn_tr, bn_1, bnpart, out1);
  }
}